// Round 1
// baseline (837.932 us; speedup 1.0000x reference)
//
#include <hip/hip_runtime.h>
#include <hip/hip_bf16.h>
#include <math.h>

#define T_DIM 512
#define B_DIM 32
#define D_DIM 1024
#define N_DIM 256
#define M_DIM (T_DIM * B_DIM)   // 16384 rows of x

// ---------------------------------------------------------------------------
// Kernel 1: fp32 projection GEMM.
// C = x[M, D] @ W^T for W in {Wk, Wv, Wq} (each [N, D], K-contiguous).
// BM=BN=128, BK=16, 256 threads, 8x8 microtile.
// LDS tiles stored transposed As[kk][pos(row)] with a split-fragment column
// permutation so the 8-wide fragments are read as two b128s 64 apart
// (<=2-way bank conflicts on both reads and writes).
// grid = (M/128, 6): blockIdx.y 0-1 -> Wk, 2-3 -> Wv, 4-5 -> Wq.
// ---------------------------------------------------------------------------
__global__ __launch_bounds__(256) void proj_gemm(
    const float* __restrict__ x,
    const float* __restrict__ Wk, const float* __restrict__ Wv,
    const float* __restrict__ Wq,
    float* __restrict__ ok, float* __restrict__ ov, float* __restrict__ oq) {
  __shared__ float As[16][132];
  __shared__ float Bs[16][132];

  const int tid = threadIdx.x;
  const int tx = tid & 15;   // output col group (8 cols)
  const int ty = tid >> 4;   // output row group (8 rows)

  const int mb  = blockIdx.x * 128;
  const int mat = blockIdx.y >> 1;          // 0,1,2 -> k,v,q
  const int nb  = (blockIdx.y & 1) * 128;   // col base within the 256-wide W

  const float* W = (mat == 0) ? Wk : (mat == 1) ? Wv : Wq;
  float*       C = (mat == 0) ? ok : (mat == 1) ? ov : oq;

  // global staging: thread loads 8 floats of one row (A) and one row (B)
  const int lr = tid >> 1;        // 0..127 : tile row
  const int lc = (tid & 1) * 8;   // 0 or 8 : kk sub-range
  // split-fragment position: row r=8a+u -> u<4 ? a*4+u : 64+a*4+(u-4)
  const int posr = ((lr >> 3) << 2) | (lr & 3) | ((lr & 4) << 4);

  const float* ap = x + (size_t)(mb + lr) * D_DIM + lc;
  const float* bp = W + (size_t)(nb + lr) * D_DIM + lc;

  float acc[8][8];
  #pragma unroll
  for (int i = 0; i < 8; ++i)
    #pragma unroll
    for (int j = 0; j < 8; ++j) acc[i][j] = 0.f;

  for (int kt = 0; kt < D_DIM; kt += 16) {
    const float4 a0 = *reinterpret_cast<const float4*>(ap + kt);
    const float4 a1 = *reinterpret_cast<const float4*>(ap + kt + 4);
    const float4 b0 = *reinterpret_cast<const float4*>(bp + kt);
    const float4 b1 = *reinterpret_cast<const float4*>(bp + kt + 4);
    __syncthreads();
    {
      const float av[8] = {a0.x, a0.y, a0.z, a0.w, a1.x, a1.y, a1.z, a1.w};
      const float bv[8] = {b0.x, b0.y, b0.z, b0.w, b1.x, b1.y, b1.z, b1.w};
      #pragma unroll
      for (int u = 0; u < 8; ++u) {
        As[lc + u][posr] = av[u];
        Bs[lc + u][posr] = bv[u];
      }
    }
    __syncthreads();
    #pragma unroll
    for (int kk = 0; kk < 16; ++kk) {
      const float4 alo = *reinterpret_cast<const float4*>(&As[kk][ty * 4]);
      const float4 ahi = *reinterpret_cast<const float4*>(&As[kk][64 + ty * 4]);
      const float4 blo = *reinterpret_cast<const float4*>(&Bs[kk][tx * 4]);
      const float4 bhi = *reinterpret_cast<const float4*>(&Bs[kk][64 + tx * 4]);
      const float a[8] = {alo.x, alo.y, alo.z, alo.w, ahi.x, ahi.y, ahi.z, ahi.w};
      const float b[8] = {blo.x, blo.y, blo.z, blo.w, bhi.x, bhi.y, bhi.z, bhi.w};
      #pragma unroll
      for (int i = 0; i < 8; ++i)
        #pragma unroll
        for (int j = 0; j < 8; ++j)
          acc[i][j] = fmaf(a[i], b[j], acc[i][j]);
    }
  }

  // store: thread owns rows mb+8ty..+7, cols nb+8tx..+7 of the 256-wide target
  #pragma unroll
  for (int i = 0; i < 8; ++i) {
    float* dst = C + (size_t)(mb + 8 * ty + i) * N_DIM + nb + 8 * tx;
    *reinterpret_cast<float4*>(dst)     = make_float4(acc[i][0], acc[i][1], acc[i][2], acc[i][3]);
    *reinterpret_cast<float4*>(dst + 4) = make_float4(acc[i][4], acc[i][5], acc[i][6], acc[i][7]);
  }
}

// ---------------------------------------------------------------------------
// Kernel 2: normalize k rows in place: k / (||k||_2 + 1e-6). One wave per row.
// ---------------------------------------------------------------------------
__global__ __launch_bounds__(256) void knorm_kernel(float* __restrict__ k) {
  const int w    = threadIdx.x >> 6;
  const int lane = threadIdx.x & 63;
  const int row  = blockIdx.x * 4 + w;
  float* p = k + (size_t)row * N_DIM + lane * 4;
  float4 f = *reinterpret_cast<const float4*>(p);
  float ss = f.x * f.x + f.y * f.y + f.z * f.z + f.w * f.w;
  #pragma unroll
  for (int m = 1; m < 64; m <<= 1) ss += __shfl_xor(ss, m, 64);
  const float inv = 1.0f / (sqrtf(ss) + 1e-6f);
  f.x *= inv; f.y *= inv; f.z *= inv; f.w *= inv;
  *reinterpret_cast<float4*>(p) = f;
}

// ---------------------------------------------------------------------------
// Kernel 3: the recurrence. State row (b,i) is independent of all others.
// 16 lanes per row, 16 state floats per lane (in VGPRs). 4 rows per wave.
// Per step: dot(S,kn) -> 4-step shfl_xor reduce -> rank-1 update -> dot(S,q)
// -> reduce -> silu readout. No barriers anywhere.
// grid = B*16 blocks x 256 threads (16 rows per block).
// ---------------------------------------------------------------------------
__global__ __launch_bounds__(256) void scan_kernel(
    const float* __restrict__ kn, const float* __restrict__ v,
    const float* __restrict__ q, const float* __restrict__ S0,
    float* __restrict__ out) {
  const int tid = threadIdx.x;
  const int g = tid >> 4;                     // row group within block
  const int l = tid & 15;                     // lane within row
  const int b = blockIdx.x >> 4;              // batch
  const int i = ((blockIdx.x & 15) << 4) | g; // state row 0..255

  float S[16];
  {
    const float* s0p = S0 + ((size_t)b * N_DIM + i) * N_DIM + l * 16;
    #pragma unroll
    for (int u = 0; u < 4; ++u) {
      const float4 f = *reinterpret_cast<const float4*>(s0p + 4 * u);
      S[4 * u + 0] = f.x; S[4 * u + 1] = f.y;
      S[4 * u + 2] = f.z; S[4 * u + 3] = f.w;
    }
  }

  const int st = B_DIM * N_DIM;  // 8192 floats per t
  const float* knp = kn + (size_t)b * N_DIM + l * 16;
  const float* qp  = q  + (size_t)b * N_DIM + l * 16;
  const float* vp  = v  + (size_t)b * N_DIM + i;
  float* op = out + (size_t)b * N_DIM + i;

  #pragma unroll 2
  for (int t = 0; t < T_DIM; ++t) {
    const size_t off = (size_t)t * st;
    float kv[16], qv[16];
    #pragma unroll
    for (int u = 0; u < 4; ++u) {
      const float4 fk = *reinterpret_cast<const float4*>(knp + off + 4 * u);
      kv[4 * u + 0] = fk.x; kv[4 * u + 1] = fk.y;
      kv[4 * u + 2] = fk.z; kv[4 * u + 3] = fk.w;
      const float4 fq = *reinterpret_cast<const float4*>(qp + off + 4 * u);
      qv[4 * u + 0] = fq.x; qv[4 * u + 1] = fq.y;
      qv[4 * u + 2] = fq.z; qv[4 * u + 3] = fq.w;
    }
    const float vi = vp[off];

    // retrieved = dot(S, kn) over this lane's 16 elems, 4 accumulators
    float r0 = 0.f, r1 = 0.f, r2 = 0.f, r3 = 0.f;
    #pragma unroll
    for (int u = 0; u < 4; ++u) {
      r0 = fmaf(S[4 * u + 0], kv[4 * u + 0], r0);
      r1 = fmaf(S[4 * u + 1], kv[4 * u + 1], r1);
      r2 = fmaf(S[4 * u + 2], kv[4 * u + 2], r2);
      r3 = fmaf(S[4 * u + 3], kv[4 * u + 3], r3);
    }
    float r = (r0 + r1) + (r2 + r3);
    #pragma unroll
    for (int m = 1; m < 16; m <<= 1) r += __shfl_xor(r, m, 64);

    const float d = vi - r;

    // rank-1 update fused with the q-readout dot
    float s0 = 0.f, s1 = 0.f, s2 = 0.f, s3 = 0.f;
    #pragma unroll
    for (int u = 0; u < 4; ++u) {
      S[4 * u + 0] = fmaf(d, kv[4 * u + 0], S[4 * u + 0]);
      s0 = fmaf(S[4 * u + 0], qv[4 * u + 0], s0);
      S[4 * u + 1] = fmaf(d, kv[4 * u + 1], S[4 * u + 1]);
      s1 = fmaf(S[4 * u + 1], qv[4 * u + 1], s1);
      S[4 * u + 2] = fmaf(d, kv[4 * u + 2], S[4 * u + 2]);
      s2 = fmaf(S[4 * u + 2], qv[4 * u + 2], s2);
      S[4 * u + 3] = fmaf(d, kv[4 * u + 3], S[4 * u + 3]);
      s3 = fmaf(S[4 * u + 3], qv[4 * u + 3], s3);
    }
    float sq = (s0 + s1) + (s2 + s3);
    #pragma unroll
    for (int m = 1; m < 16; m <<= 1) sq += __shfl_xor(sq, m, 64);

    // out = Sq * silu(Sq) = Sq^2 * sigmoid(Sq)
    const float sig = 1.0f / (1.0f + __expf(-sq));
    if (l == 0) op[off] = sq * sq * sig;
  }
}

// ---------------------------------------------------------------------------
extern "C" void kernel_launch(void* const* d_in, const int* in_sizes, int n_in,
                              void* d_out, int out_size, void* d_ws, size_t ws_size,
                              hipStream_t stream) {
  (void)in_sizes; (void)n_in; (void)out_size; (void)ws_size;
  const float* x  = (const float*)d_in[0];
  const float* S0 = (const float*)d_in[1];
  const float* Wk = (const float*)d_in[2];
  const float* Wv = (const float*)d_in[3];
  const float* Wq = (const float*)d_in[4];
  float* outp = (float*)d_out;

  // workspace: kn | v | q, each M*N floats (16.78 MB) -> 50.3 MB total
  float* kn = (float*)d_ws;
  float* vv = kn + (size_t)M_DIM * N_DIM;
  float* qq = vv + (size_t)M_DIM * N_DIM;

  dim3 gg(M_DIM / 128, 6);
  proj_gemm<<<gg, 256, 0, stream>>>(x, Wk, Wv, Wq, kn, vv, qq);
  knorm_kernel<<<M_DIM / 4, 256, 0, stream>>>(kn);
  scan_kernel<<<B_DIM * 16, 256, 0, stream>>>(kn, vv, qq, S0, outp);
}

// Round 2
// 758.252 us; speedup vs baseline: 1.1051x; 1.1051x over previous
//
#include <hip/hip_runtime.h>
#include <hip/hip_bf16.h>
#include <math.h>

#define T_DIM 512
#define B_DIM 32
#define D_DIM 1024
#define N_DIM 256
#define M_DIM (T_DIM * B_DIM)   // 16384 rows of x

// ---------------------------------------------------------------------------
// Kernel 1: fp32 projection GEMM (unchanged from round 1 — ~95 TF fp32).
// ---------------------------------------------------------------------------
__global__ __launch_bounds__(256) void proj_gemm(
    const float* __restrict__ x,
    const float* __restrict__ Wk, const float* __restrict__ Wv,
    const float* __restrict__ Wq,
    float* __restrict__ ok, float* __restrict__ ov, float* __restrict__ oq) {
  __shared__ float As[16][132];
  __shared__ float Bs[16][132];

  const int tid = threadIdx.x;
  const int tx = tid & 15;   // output col group (8 cols)
  const int ty = tid >> 4;   // output row group (8 rows)

  const int mb  = blockIdx.x * 128;
  const int mat = blockIdx.y >> 1;          // 0,1,2 -> k,v,q
  const int nb  = (blockIdx.y & 1) * 128;   // col base within the 256-wide W

  const float* W = (mat == 0) ? Wk : (mat == 1) ? Wv : Wq;
  float*       C = (mat == 0) ? ok : (mat == 1) ? ov : oq;

  const int lr = tid >> 1;        // 0..127 : tile row
  const int lc = (tid & 1) * 8;   // 0 or 8 : kk sub-range
  const int posr = ((lr >> 3) << 2) | (lr & 3) | ((lr & 4) << 4);

  const float* ap = x + (size_t)(mb + lr) * D_DIM + lc;
  const float* bp = W + (size_t)(nb + lr) * D_DIM + lc;

  float acc[8][8];
  #pragma unroll
  for (int i = 0; i < 8; ++i)
    #pragma unroll
    for (int j = 0; j < 8; ++j) acc[i][j] = 0.f;

  for (int kt = 0; kt < D_DIM; kt += 16) {
    const float4 a0 = *reinterpret_cast<const float4*>(ap + kt);
    const float4 a1 = *reinterpret_cast<const float4*>(ap + kt + 4);
    const float4 b0 = *reinterpret_cast<const float4*>(bp + kt);
    const float4 b1 = *reinterpret_cast<const float4*>(bp + kt + 4);
    __syncthreads();
    {
      const float av[8] = {a0.x, a0.y, a0.z, a0.w, a1.x, a1.y, a1.z, a1.w};
      const float bv[8] = {b0.x, b0.y, b0.z, b0.w, b1.x, b1.y, b1.z, b1.w};
      #pragma unroll
      for (int u = 0; u < 8; ++u) {
        As[lc + u][posr] = av[u];
        Bs[lc + u][posr] = bv[u];
      }
    }
    __syncthreads();
    #pragma unroll
    for (int kk = 0; kk < 16; ++kk) {
      const float4 alo = *reinterpret_cast<const float4*>(&As[kk][ty * 4]);
      const float4 ahi = *reinterpret_cast<const float4*>(&As[kk][64 + ty * 4]);
      const float4 blo = *reinterpret_cast<const float4*>(&Bs[kk][tx * 4]);
      const float4 bhi = *reinterpret_cast<const float4*>(&Bs[kk][64 + tx * 4]);
      const float a[8] = {alo.x, alo.y, alo.z, alo.w, ahi.x, ahi.y, ahi.z, ahi.w};
      const float b[8] = {blo.x, blo.y, blo.z, blo.w, bhi.x, bhi.y, bhi.z, bhi.w};
      #pragma unroll
      for (int i = 0; i < 8; ++i)
        #pragma unroll
        for (int j = 0; j < 8; ++j)
          acc[i][j] = fmaf(a[i], b[j], acc[i][j]);
    }
  }

  #pragma unroll
  for (int i = 0; i < 8; ++i) {
    float* dst = C + (size_t)(mb + 8 * ty + i) * N_DIM + nb + 8 * tx;
    *reinterpret_cast<float4*>(dst)     = make_float4(acc[i][0], acc[i][1], acc[i][2], acc[i][3]);
    *reinterpret_cast<float4*>(dst + 4) = make_float4(acc[i][4], acc[i][5], acc[i][6], acc[i][7]);
  }
}

// ---------------------------------------------------------------------------
// Kernel 2: normalize k rows in place: k / (||k||_2 + 1e-6). One wave per row.
// ---------------------------------------------------------------------------
__global__ __launch_bounds__(256) void knorm_kernel(float* __restrict__ k) {
  const int w    = threadIdx.x >> 6;
  const int lane = threadIdx.x & 63;
  const int row  = blockIdx.x * 4 + w;
  float* p = k + (size_t)row * N_DIM + lane * 4;
  float4 f = *reinterpret_cast<const float4*>(p);
  float ss = f.x * f.x + f.y * f.y + f.z * f.z + f.w * f.w;
  #pragma unroll
  for (int m = 1; m < 64; m <<= 1) ss += __shfl_xor(ss, m, 64);
  const float inv = 1.0f / (sqrtf(ss) + 1e-6f);
  f.x *= inv; f.y *= inv; f.z *= inv; f.w *= inv;
  *reinterpret_cast<float4*>(p) = f;
}

// ---------------------------------------------------------------------------
// Kernel 3: the recurrence.
// Round-2 change: cross-lane reductions via DPP16 VALU butterflies instead of
// __shfl_xor (ds_bpermute, ~120cyc LDS-unit latency each -> was the critical
// path: 8 chained DS ops/step). DPP add is ~4-8 cyc VALU. Row groups are
// 16-lane aligned, so quad_perm/mirror patterns never cross a DPP row.
// Also: hand ping-pong prefetch of (kn,q,v) for step t+1 during compute of t.
// ---------------------------------------------------------------------------
__device__ __forceinline__ float row16_reduce(float x) {
  int y;
  y = __builtin_amdgcn_update_dpp(0, __float_as_int(x), 0xB1, 0xF, 0xF, true);  // quad_perm [1,0,3,2]: xor1
  x += __int_as_float(y);
  y = __builtin_amdgcn_update_dpp(0, __float_as_int(x), 0x4E, 0xF, 0xF, true);  // quad_perm [2,3,0,1]: xor2
  x += __int_as_float(y);
  y = __builtin_amdgcn_update_dpp(0, __float_as_int(x), 0x141, 0xF, 0xF, true); // row_half_mirror: xor7 (~xor4)
  x += __int_as_float(y);
  y = __builtin_amdgcn_update_dpp(0, __float_as_int(x), 0x140, 0xF, 0xF, true); // row_mirror: xor15 (~xor8)
  x += __int_as_float(y);
  return x;  // all 16 lanes of the row hold the full sum
}

__device__ __forceinline__ void scan_step(float S[16],
                                          const float4 kf[4], const float4 qf[4],
                                          float vi, bool lane0, float* op) {
  float kv[16], qv[16];
  #pragma unroll
  for (int u = 0; u < 4; ++u) {
    kv[4 * u + 0] = kf[u].x; kv[4 * u + 1] = kf[u].y;
    kv[4 * u + 2] = kf[u].z; kv[4 * u + 3] = kf[u].w;
    qv[4 * u + 0] = qf[u].x; qv[4 * u + 1] = qf[u].y;
    qv[4 * u + 2] = qf[u].z; qv[4 * u + 3] = qf[u].w;
  }

  // retrieved = dot(S, kn), 4 independent accumulator chains
  float r0 = 0.f, r1 = 0.f, r2 = 0.f, r3 = 0.f;
  #pragma unroll
  for (int u = 0; u < 4; ++u) {
    r0 = fmaf(S[4 * u + 0], kv[4 * u + 0], r0);
    r1 = fmaf(S[4 * u + 1], kv[4 * u + 1], r1);
    r2 = fmaf(S[4 * u + 2], kv[4 * u + 2], r2);
    r3 = fmaf(S[4 * u + 3], kv[4 * u + 3], r3);
  }
  const float r = row16_reduce((r0 + r1) + (r2 + r3));
  const float d = vi - r;

  // rank-1 update fused with q-readout dot
  float s0 = 0.f, s1 = 0.f, s2 = 0.f, s3 = 0.f;
  #pragma unroll
  for (int u = 0; u < 4; ++u) {
    S[4 * u + 0] = fmaf(d, kv[4 * u + 0], S[4 * u + 0]);
    s0 = fmaf(S[4 * u + 0], qv[4 * u + 0], s0);
    S[4 * u + 1] = fmaf(d, kv[4 * u + 1], S[4 * u + 1]);
    s1 = fmaf(S[4 * u + 1], qv[4 * u + 1], s1);
    S[4 * u + 2] = fmaf(d, kv[4 * u + 2], S[4 * u + 2]);
    s2 = fmaf(S[4 * u + 2], qv[4 * u + 2], s2);
    S[4 * u + 3] = fmaf(d, kv[4 * u + 3], S[4 * u + 3]);
    s3 = fmaf(S[4 * u + 3], qv[4 * u + 3], s3);
  }
  // Sq reduce + silu are OFF the inter-step chain (next step needs only S)
  const float sq = row16_reduce((s0 + s1) + (s2 + s3));
  const float sig = __builtin_amdgcn_rcpf(1.0f + __expf(-sq));
  if (lane0) *op = sq * sq * sig;
}

__global__ __launch_bounds__(256) void scan_kernel(
    const float* __restrict__ kn, const float* __restrict__ v,
    const float* __restrict__ q, const float* __restrict__ S0,
    float* __restrict__ out) {
  const int tid = threadIdx.x;
  const int g = tid >> 4;                     // row group within block
  const int l = tid & 15;                     // lane within row
  const int b = blockIdx.x >> 4;              // batch
  const int i = ((blockIdx.x & 15) << 4) | g; // state row 0..255
  const bool lane0 = (l == 0);

  float S[16];
  {
    const float* s0p = S0 + ((size_t)b * N_DIM + i) * N_DIM + l * 16;
    #pragma unroll
    for (int u = 0; u < 4; ++u) {
      const float4 f = *reinterpret_cast<const float4*>(s0p + 4 * u);
      S[4 * u + 0] = f.x; S[4 * u + 1] = f.y;
      S[4 * u + 2] = f.z; S[4 * u + 3] = f.w;
    }
  }

  const int st = B_DIM * N_DIM;  // 8192 floats per t
  const float* knp = kn + b * N_DIM + l * 16;
  const float* qp  = q  + b * N_DIM + l * 16;
  const float* vp  = v  + b * N_DIM + i;
  float* op = out + b * N_DIM + i;

  float4 ka[4], qa[4]; float va;
  #pragma unroll
  for (int u = 0; u < 4; ++u) {
    ka[u] = *reinterpret_cast<const float4*>(knp + 4 * u);
    qa[u] = *reinterpret_cast<const float4*>(qp + 4 * u);
  }
  va = vp[0];

  for (int t = 0; t < T_DIM; t += 2) {
    // prefetch t+1 into B while computing t from A
    float4 kb[4], qb[4]; float vb;
    {
      const int o1 = (t + 1) * st;
      #pragma unroll
      for (int u = 0; u < 4; ++u) {
        kb[u] = *reinterpret_cast<const float4*>(knp + o1 + 4 * u);
        qb[u] = *reinterpret_cast<const float4*>(qp + o1 + 4 * u);
      }
      vb = vp[o1];
    }
    scan_step(S, ka, qa, va, lane0, op + (size_t)t * st);

    // prefetch t+2 into A while computing t+1 from B (clamp at last step)
    {
      const int t2 = (t + 2 < T_DIM) ? (t + 2) : (T_DIM - 1);
      const int o2 = t2 * st;
      #pragma unroll
      for (int u = 0; u < 4; ++u) {
        ka[u] = *reinterpret_cast<const float4*>(knp + o2 + 4 * u);
        qa[u] = *reinterpret_cast<const float4*>(qp + o2 + 4 * u);
      }
      va = vp[o2];
    }
    scan_step(S, kb, qb, vb, lane0, op + (size_t)(t + 1) * st);
  }
}

// ---------------------------------------------------------------------------
extern "C" void kernel_launch(void* const* d_in, const int* in_sizes, int n_in,
                              void* d_out, int out_size, void* d_ws, size_t ws_size,
                              hipStream_t stream) {
  (void)in_sizes; (void)n_in; (void)out_size; (void)ws_size;
  const float* x  = (const float*)d_in[0];
  const float* S0 = (const float*)d_in[1];
  const float* Wk = (const float*)d_in[2];
  const float* Wv = (const float*)d_in[3];
  const float* Wq = (const float*)d_in[4];
  float* outp = (float*)d_out;

  float* kn = (float*)d_ws;
  float* vv = kn + (size_t)M_DIM * N_DIM;
  float* qq = vv + (size_t)M_DIM * N_DIM;

  dim3 gg(M_DIM / 128, 6);
  proj_gemm<<<gg, 256, 0, stream>>>(x, Wk, Wv, Wq, kn, vv, qq);
  knorm_kernel<<<M_DIM / 4, 256, 0, stream>>>(kn);
  scan_kernel<<<B_DIM * 16, 256, 0, stream>>>(kn, vv, qq, S0, outp);
}

// Round 3
// 393.324 us; speedup vs baseline: 2.1304x; 1.9278x over previous
//
#include <hip/hip_runtime.h>
#include <hip/hip_bf16.h>
#include <math.h>

#define T_DIM 512
#define B_DIM 32
#define D_DIM 1024
#define N_DIM 256
#define M_DIM (T_DIM * B_DIM)
#define CHUNK 32
#define NCHUNK (T_DIM / CHUNK)   // 16
#define IBLK 32
#define ST (B_DIM * N_DIM)       // 8192 floats: t-stride in kn/v/q/out

typedef _Float16 f16;
typedef _Float16 f16x8 __attribute__((ext_vector_type(8)));
typedef _Float16 f16x4 __attribute__((ext_vector_type(4)));
typedef float    f32x4 __attribute__((ext_vector_type(4)));

#define LDK 264   // halves/row for Kh/Qh/Sh   (33 quads of 16B - odd -> conflict-free)
#define LDT 40    // halves/row for KhT/W/G/U0T/UT (5 quads - odd)
#define LDV 36    // floats/row for Vl (9 quads - odd)

__device__ __forceinline__ f16x8 cvt8(const float4& a, const float4& b) {
  f16x8 h;
  h[0] = (f16)a.x; h[1] = (f16)a.y; h[2] = (f16)a.z; h[3] = (f16)a.w;
  h[4] = (f16)b.x; h[5] = (f16)b.y; h[6] = (f16)b.z; h[7] = (f16)b.w;
  return h;
}

// ---------------------------------------------------------------------------
// Kernel 1: fp32 projection GEMM (unchanged; ~95 TF -> target next round).
// ---------------------------------------------------------------------------
__global__ __launch_bounds__(256) void proj_gemm(
    const float* __restrict__ x,
    const float* __restrict__ Wk, const float* __restrict__ Wv,
    const float* __restrict__ Wq,
    float* __restrict__ ok, float* __restrict__ ov, float* __restrict__ oq) {
  __shared__ float As[16][132];
  __shared__ float Bs[16][132];

  const int tid = threadIdx.x;
  const int tx = tid & 15;
  const int ty = tid >> 4;

  const int mb  = blockIdx.x * 128;
  const int mat = blockIdx.y >> 1;
  const int nb  = (blockIdx.y & 1) * 128;

  const float* W = (mat == 0) ? Wk : (mat == 1) ? Wv : Wq;
  float*       C = (mat == 0) ? ok : (mat == 1) ? ov : oq;

  const int lr = tid >> 1;
  const int lc = (tid & 1) * 8;
  const int posr = ((lr >> 3) << 2) | (lr & 3) | ((lr & 4) << 4);

  const float* ap = x + (size_t)(mb + lr) * D_DIM + lc;
  const float* bp = W + (size_t)(nb + lr) * D_DIM + lc;

  float acc[8][8];
  #pragma unroll
  for (int i = 0; i < 8; ++i)
    #pragma unroll
    for (int j = 0; j < 8; ++j) acc[i][j] = 0.f;

  for (int kt = 0; kt < D_DIM; kt += 16) {
    const float4 a0 = *reinterpret_cast<const float4*>(ap + kt);
    const float4 a1 = *reinterpret_cast<const float4*>(ap + kt + 4);
    const float4 b0 = *reinterpret_cast<const float4*>(bp + kt);
    const float4 b1 = *reinterpret_cast<const float4*>(bp + kt + 4);
    __syncthreads();
    {
      const float av[8] = {a0.x, a0.y, a0.z, a0.w, a1.x, a1.y, a1.z, a1.w};
      const float bv[8] = {b0.x, b0.y, b0.z, b0.w, b1.x, b1.y, b1.z, b1.w};
      #pragma unroll
      for (int u = 0; u < 8; ++u) {
        As[lc + u][posr] = av[u];
        Bs[lc + u][posr] = bv[u];
      }
    }
    __syncthreads();
    #pragma unroll
    for (int kk = 0; kk < 16; ++kk) {
      const float4 alo = *reinterpret_cast<const float4*>(&As[kk][ty * 4]);
      const float4 ahi = *reinterpret_cast<const float4*>(&As[kk][64 + ty * 4]);
      const float4 blo = *reinterpret_cast<const float4*>(&Bs[kk][tx * 4]);
      const float4 bhi = *reinterpret_cast<const float4*>(&Bs[kk][64 + tx * 4]);
      const float a[8] = {alo.x, alo.y, alo.z, alo.w, ahi.x, ahi.y, ahi.z, ahi.w};
      const float b[8] = {blo.x, blo.y, blo.z, blo.w, bhi.x, bhi.y, bhi.z, bhi.w};
      #pragma unroll
      for (int i = 0; i < 8; ++i)
        #pragma unroll
        for (int j = 0; j < 8; ++j)
          acc[i][j] = fmaf(a[i], b[j], acc[i][j]);
    }
  }

  #pragma unroll
  for (int i = 0; i < 8; ++i) {
    float* dst = C + (size_t)(mb + 8 * ty + i) * N_DIM + nb + 8 * tx;
    *reinterpret_cast<float4*>(dst)     = make_float4(acc[i][0], acc[i][1], acc[i][2], acc[i][3]);
    *reinterpret_cast<float4*>(dst + 4) = make_float4(acc[i][4], acc[i][5], acc[i][6], acc[i][7]);
  }
}

// ---------------------------------------------------------------------------
// Kernel 2: k-row L2 normalize (unchanged).
// ---------------------------------------------------------------------------
__global__ __launch_bounds__(256) void knorm_kernel(float* __restrict__ k) {
  const int w    = threadIdx.x >> 6;
  const int lane = threadIdx.x & 63;
  const int row  = blockIdx.x * 4 + w;
  float* p = k + (size_t)row * N_DIM + lane * 4;
  float4 f = *reinterpret_cast<const float4*>(p);
  float ss = f.x * f.x + f.y * f.y + f.z * f.z + f.w * f.w;
  #pragma unroll
  for (int m = 1; m < 64; m <<= 1) ss += __shfl_xor(ss, m, 64);
  const float inv = 1.0f / (sqrtf(ss) + 1e-6f);
  f.x *= inv; f.y *= inv; f.z *= inv; f.w *= inv;
  *reinterpret_cast<float4*>(p) = f;
}

// ---------------------------------------------------------------------------
// Kernel 3: per-(batch,chunk) precompute of the WY factors:
//   A = stril(K K^T)  (fp32, LDS)          [k normalized -> |A| <= 1]
//   W = (I + A)^{-1}  (forward substitution, fp32 regs -> fp16 ws)
//   G = tril(Q K^T)   (inclusive, fp16 ws)
// grid = 32*16 = 512 blocks x 256 thr. No serial dependency across blocks.
// ---------------------------------------------------------------------------
__global__ __launch_bounds__(256, 2) void precompute_wg(
    const float* __restrict__ kn, const float* __restrict__ q,
    f16* __restrict__ Wg, f16* __restrict__ Gg) {
  __shared__ __align__(16) f16 Kh[32 * LDK];
  __shared__ __align__(16) f16 Qh[32 * LDK];
  __shared__ float Al[32 * 33];

  const int tid  = threadIdx.x;
  const int lane = tid & 63;
  const int w    = tid >> 6;
  const int lr   = lane & 15;
  const int lq   = lane >> 4;
  const int tm   = w >> 1, tn = w & 1;
  const int b    = blockIdx.x >> 4;
  const int c    = blockIdx.x & 15;
  const int t0g  = c * CHUNK;

  // stage K, Q rows (fp32 global -> fp16 LDS, padded rows)
  {
    const int t = tid >> 3, cg = tid & 7;
    const float* ks = kn + (size_t)(t0g + t) * ST + b * N_DIM + cg * 32;
    const float* qs = q  + (size_t)(t0g + t) * ST + b * N_DIM + cg * 32;
    #pragma unroll
    for (int m = 0; m < 4; ++m) {
      float4 f0 = *(const float4*)(ks + 8 * m);
      float4 f1 = *(const float4*)(ks + 8 * m + 4);
      *(f16x8*)&Kh[t * LDK + cg * 32 + 8 * m] = cvt8(f0, f1);
      float4 g0 = *(const float4*)(qs + 8 * m);
      float4 g1 = *(const float4*)(qs + 8 * m + 4);
      *(f16x8*)&Qh[t * LDK + cg * 32 + 8 * m] = cvt8(g0, g1);
    }
  }
  __syncthreads();

  // A = K K^T, G = Q K^T : one 16x16 tile per wave, 8 k-iters
  f32x4 Aa = {0.f, 0.f, 0.f, 0.f}, Ga = {0.f, 0.f, 0.f, 0.f};
  #pragma unroll
  for (int kk = 0; kk < 8; ++kk) {
    f16x8 ka = *(const f16x8*)&Kh[(16 * tm + lr) * LDK + 32 * kk + 8 * lq];
    f16x8 qa = *(const f16x8*)&Qh[(16 * tm + lr) * LDK + 32 * kk + 8 * lq];
    f16x8 kb = *(const f16x8*)&Kh[(16 * tn + lr) * LDK + 32 * kk + 8 * lq];
    Aa = __builtin_amdgcn_mfma_f32_16x16x32_f16(ka, kb, Aa, 0, 0, 0);
    Ga = __builtin_amdgcn_mfma_f32_16x16x32_f16(qa, kb, Ga, 0, 0, 0);
  }
  {
    const int s = 16 * tn + lr;
    f16* gdst = Gg + (size_t)blockIdx.x * 1280;
    #pragma unroll
    for (int r = 0; r < 4; ++r) {
      const int t = 16 * tm + 4 * lq + r;
      Al[t * 33 + s] = (s < t) ? Aa[r] : 0.f;              // strict lower
      gdst[t * LDT + s] = (f16)((s <= t) ? Ga[r] : 0.f);   // inclusive lower
    }
  }
  __syncthreads();

  // W = (I+L)^{-1} columnwise: lane j holds column j in registers.
  if (tid < 32) {
    float wv[32];
    f16* wdst = Wg + (size_t)blockIdx.x * 1280;
    #pragma unroll
    for (int t = 0; t < 32; ++t) {
      float s0 = 0.f, s1 = 0.f, s2 = 0.f, s3 = 0.f;
      #pragma unroll
      for (int s = 0; s < 32; ++s) {   // only s<t contributes (Al has strict mask anyway)
        if (s >= t) break;
        const float a = Al[t * 33 + s];
        if ((s & 3) == 0) s0 = fmaf(a, wv[s], s0);
        else if ((s & 3) == 1) s1 = fmaf(a, wv[s], s1);
        else if ((s & 3) == 2) s2 = fmaf(a, wv[s], s2);
        else s3 = fmaf(a, wv[s], s3);
      }
      wv[t] = ((t == tid) ? 1.f : 0.f) - ((s0 + s1) + (s2 + s3));
    }
    #pragma unroll
    for (int t = 0; t < 32; ++t) wdst[t * LDT + tid] = (f16)wv[t];
  }
}

// ---------------------------------------------------------------------------
// Kernel 4: chunked delta-rule scan. grid = 256 blocks (bid = iblk*32 + b so
// the 8 row-block sharers of a (b,chunk) K/Q tile land on one XCD for L2
// reuse), 256 thr (4 waves). S0 block [32 i x 256 j] fp32 lives in REGISTERS
// (8 f32x4 tiles/thread, wave w owns j in [64w,64w+64)); fp16 shadow Sh in
// LDS serves MFMA B-operands. Per chunk: 4 barriers, 26 MFMAs/wave.
// ---------------------------------------------------------------------------
__global__ __launch_bounds__(256, 1) void scan_chunked(
    const float* __restrict__ kn, const float* __restrict__ v,
    const float* __restrict__ q, const float* __restrict__ S0,
    const f16* __restrict__ Wg, const f16* __restrict__ Gg,
    float* __restrict__ out) {
  __shared__ __align__(16) f16 Kh[32 * LDK];
  __shared__ __align__(16) f16 Qh[32 * LDK];
  __shared__ __align__(16) f16 Sh[32 * LDK];
  __shared__ __align__(16) f16 KhT[256 * LDT];
  __shared__ __align__(16) f16 Wl[32 * LDT];
  __shared__ __align__(16) f16 Gl[32 * LDT];
  __shared__ __align__(16) f16 U0T[32 * LDT];
  __shared__ __align__(16) f16 UT[32 * LDT];
  __shared__ __align__(16) float Vl[32 * LDV];

  const int tid  = threadIdx.x;
  const int lane = tid & 63;
  const int w    = tid >> 6;         // wave 0..3
  const int lr   = lane & 15;
  const int lq   = lane >> 4;
  const int tm   = w >> 1, tn = w & 1;
  const int b    = blockIdx.x & 31;
  const int i0   = (blockIdx.x >> 5) * IBLK;

  // ---- S0 master into registers (wave w: j in [64w, 64w+64)), Sh shadow
  f32x4 acc[2][4];
  const float* S0b = S0 + (size_t)b * N_DIM * N_DIM + (size_t)i0 * N_DIM;
  #pragma unroll
  for (int ti = 0; ti < 2; ++ti)
    #pragma unroll
    for (int jt = 0; jt < 4; ++jt)
      #pragma unroll
      for (int r = 0; r < 4; ++r) {
        const int i = 16 * ti + 4 * lq + r;
        const int j = 64 * w + 16 * jt + lr;
        acc[ti][jt][r] = S0b[(size_t)i * N_DIM + j];
      }
  {
    const int i = tid >> 3, cg = tid & 7;
    const float* ss = S0b + (size_t)i * N_DIM + cg * 32;
    #pragma unroll
    for (int m = 0; m < 4; ++m) {
      float4 f0 = *(const float4*)(ss + 8 * m);
      float4 f1 = *(const float4*)(ss + 8 * m + 4);
      *(f16x8*)&Sh[i * LDK + cg * 32 + 8 * m] = cvt8(f0, f1);
    }
  }
  __syncthreads();

  for (int c = 0; c < NCHUNK; ++c) {
    const int t0g = c * CHUNK;
    // ---------------- stage K rows, Q rows, V block, K columns, W, G
    {
      const int t = tid >> 3, cg = tid & 7;
      const float* ks = kn + (size_t)(t0g + t) * ST + b * N_DIM + cg * 32;
      const float* qs = q  + (size_t)(t0g + t) * ST + b * N_DIM + cg * 32;
      #pragma unroll
      for (int m = 0; m < 4; ++m) {
        float4 f0 = *(const float4*)(ks + 8 * m);
        float4 f1 = *(const float4*)(ks + 8 * m + 4);
        *(f16x8*)&Kh[t * LDK + cg * 32 + 8 * m] = cvt8(f0, f1);
        float4 g0 = *(const float4*)(qs + 8 * m);
        float4 g1 = *(const float4*)(qs + 8 * m + 4);
        *(f16x8*)&Qh[t * LDK + cg * 32 + 8 * m] = cvt8(g0, g1);
      }
      float4 vf = *(const float4*)(v + (size_t)(t0g + t) * ST + b * N_DIM + i0 + cg * 4);
      *(float4*)&Vl[t * LDV + cg * 4] = vf;
    }
    {
      // K^T: thread j = tid reads its column (coalesced across lanes)
      const float* col = kn + (size_t)t0g * ST + b * N_DIM + tid;
      #pragma unroll
      for (int m = 0; m < 4; ++m) {
        f16x8 h;
        #pragma unroll
        for (int e = 0; e < 8; ++e) h[e] = (f16)col[(size_t)(8 * m + e) * ST];
        *(f16x8*)&KhT[tid * LDT + 8 * m] = h;
      }
    }
    if (tid < 160) {
      const f16x8* wsrc = (const f16x8*)(Wg + (size_t)(b * NCHUNK + c) * 1280);
      const f16x8* gsrc = (const f16x8*)(Gg + (size_t)(b * NCHUNK + c) * 1280);
      ((f16x8*)Wl)[tid] = wsrc[tid];
      ((f16x8*)Gl)[tid] = gsrc[tid];
    }
    __syncthreads();

    // ---------------- phase 1: P = K@S0^T, Oq = Q@S0^T (1 tile/wave, 8 k-iters)
    f32x4 Pacc = {0.f, 0.f, 0.f, 0.f};
    f32x4 Oq   = {0.f, 0.f, 0.f, 0.f};
    #pragma unroll
    for (int kk = 0; kk < 8; ++kk) {
      f16x8 ka = *(const f16x8*)&Kh[(16 * tm + lr) * LDK + 32 * kk + 8 * lq];
      f16x8 qa = *(const f16x8*)&Qh[(16 * tm + lr) * LDK + 32 * kk + 8 * lq];
      f16x8 sb = *(const f16x8*)&Sh[(16 * tn + lr) * LDK + 32 * kk + 8 * lq];
      Pacc = __builtin_amdgcn_mfma_f32_16x16x32_f16(ka, sb, Pacc, 0, 0, 0);
      Oq   = __builtin_amdgcn_mfma_f32_16x16x32_f16(qa, sb, Oq,   0, 0, 0);
    }
    {   // U0 = V - P, stored transposed U0T[i][t] (4 consecutive t -> b64)
      const int i = 16 * tn + lr;
      const int t0 = 16 * tm + 4 * lq;
      f16x4 u0;
      #pragma unroll
      for (int r = 0; r < 4; ++r) u0[r] = (f16)(Vl[(t0 + r) * LDV + i] - Pacc[r]);
      *(f16x4*)&U0T[i * LDT + t0] = u0;
    }
    __syncthreads();

    // ---------------- phase 2: U = W @ U0 (one MFMA/wave), store UT[i][t]
    {
      f16x8 wa = *(const f16x8*)&Wl[(16 * tm + lr) * LDT + 8 * lq];
      f16x8 ub = *(const f16x8*)&U0T[(16 * tn + lr) * LDT + 8 * lq];
      f32x4 z = {0.f, 0.f, 0.f, 0.f};
      f32x4 Ud = __builtin_amdgcn_mfma_f32_16x16x32_f16(wa, ub, z, 0, 0, 0);
      const int i = 16 * tn + lr;
      const int t0 = 16 * tm + 4 * lq;
      f16x4 uh;
      #pragma unroll
      for (int r = 0; r < 4; ++r) uh[r] = (f16)Ud[r];
      *(f16x4*)&UT[i * LDT + t0] = uh;
    }
    __syncthreads();

    // ---------------- phase 3: Out = Oq + G@U -> silu -> global
    {
      f16x8 ga = *(const f16x8*)&Gl[(16 * tm + lr) * LDT + 8 * lq];
      f16x8 ub = *(const f16x8*)&UT[(16 * tn + lr) * LDT + 8 * lq];
      f32x4 O = __builtin_amdgcn_mfma_f32_16x16x32_f16(ga, ub, Oq, 0, 0, 0);
      const int i = 16 * tn + lr;
      const int tt0 = 16 * tm + 4 * lq;
      #pragma unroll
      for (int r = 0; r < 4; ++r) {
        const float sq = O[r];
        const float sig = 1.0f / (1.0f + __expf(-sq));
        out[(size_t)(t0g + tt0 + r) * ST + b * N_DIM + i0 + i] = sq * sq * sig;
      }
    }
    // ---------------- phase 4: S0 += U^T @ K (8 MFMA/wave), refresh Sh slice
    #pragma unroll
    for (int ti = 0; ti < 2; ++ti) {
      f16x8 ua = *(const f16x8*)&UT[(16 * ti + lr) * LDT + 8 * lq];
      #pragma unroll
      for (int jt = 0; jt < 4; ++jt) {
        f16x8 kb = *(const f16x8*)&KhT[(64 * w + 16 * jt + lr) * LDT + 8 * lq];
        acc[ti][jt] = __builtin_amdgcn_mfma_f32_16x16x32_f16(ua, kb, acc[ti][jt], 0, 0, 0);
      }
    }
    #pragma unroll
    for (int ti = 0; ti < 2; ++ti)
      #pragma unroll
      for (int jt = 0; jt < 4; ++jt)
        #pragma unroll
        for (int r = 0; r < 4; ++r)
          Sh[(16 * ti + 4 * lq + r) * LDK + 64 * w + 16 * jt + lr] = (f16)acc[ti][jt][r];
    __syncthreads();
  }
}

// ---------------------------------------------------------------------------
extern "C" void kernel_launch(void* const* d_in, const int* in_sizes, int n_in,
                              void* d_out, int out_size, void* d_ws, size_t ws_size,
                              hipStream_t stream) {
  (void)in_sizes; (void)n_in; (void)out_size; (void)ws_size;
  const float* x  = (const float*)d_in[0];
  const float* S0 = (const float*)d_in[1];
  const float* Wk = (const float*)d_in[2];
  const float* Wv = (const float*)d_in[3];
  const float* Wq = (const float*)d_in[4];
  float* outp = (float*)d_out;

  // ws: kn | v | q (fp32, 3 x 16.78MB) then W | G (fp16, 1.31MB each)
  float* kn = (float*)d_ws;
  float* vv = kn + (size_t)M_DIM * N_DIM;
  float* qq = vv + (size_t)M_DIM * N_DIM;
  f16*   Wg = (f16*)(qq + (size_t)M_DIM * N_DIM);
  f16*   Gg = Wg + (size_t)B_DIM * NCHUNK * 1280;

  dim3 gg(M_DIM / 128, 6);
  proj_gemm<<<gg, 256, 0, stream>>>(x, Wk, Wv, Wq, kn, vv, qq);
  knorm_kernel<<<M_DIM / 4, 256, 0, stream>>>(kn);
  precompute_wg<<<B_DIM * NCHUNK, 256, 0, stream>>>(kn, qq, Wg, Gg);
  scan_chunked<<<B_DIM * (N_DIM / IBLK), 256, 0, stream>>>(kn, vv, qq, S0, Wg, Gg, outp);
}

// Round 4
// 211.657 us; speedup vs baseline: 3.9589x; 1.8583x over previous
//
#include <hip/hip_runtime.h>
#include <hip/hip_bf16.h>
#include <math.h>

#define T_DIM 512
#define B_DIM 32
#define D_DIM 1024
#define N_DIM 256
#define M_DIM (T_DIM * B_DIM)
#define CHUNK 32
#define NCHUNK (T_DIM / CHUNK)   // 16
#define IBLK 32
#define ST (B_DIM * N_DIM)       // 8192 floats: t-stride in kn/v/q/out
#define BK 64                    // GEMM K-tile (f16)

typedef _Float16 f16;
typedef _Float16 f16x8 __attribute__((ext_vector_type(8)));
typedef _Float16 f16x4 __attribute__((ext_vector_type(4)));
typedef float    f32x4 __attribute__((ext_vector_type(4)));

#define LDK 264   // halves/row for Kh/Qh/Sh (33 quads of 16B - odd -> conflict-free)
#define LDT 40    // halves/row for KhT/W/G/U0T/UT (5 quads - odd)
#define LDV 36    // floats/row for Vl (9 quads - odd)

__device__ __forceinline__ f16x8 cvt8(const float4& a, const float4& b) {
  f16x8 h;
  h[0] = (f16)a.x; h[1] = (f16)a.y; h[2] = (f16)a.z; h[3] = (f16)a.w;
  h[4] = (f16)b.x; h[5] = (f16)b.y; h[6] = (f16)b.z; h[7] = (f16)b.w;
  return h;
}

// ---------------------------------------------------------------------------
// Kernel 1 (round-4 rewrite): f16 MFMA projection GEMM.
// C = x[16384,1024] @ W^T, W in {Wk,Wv,Wq} ([256,1024] row-major).
// BM=BN=128, BK=64, 256 thr / 4 waves, wave = 64x64 out (4x4 16x16x32 frags).
// Reg-staged fp32->f16 into XOR-swizzled LDS (slot ^= row&7 on 16B slots):
//   writes: 8 lanes per bank-quad (conflict-free);
//   frag reads: 2 lanes/slot (2-way aliasing = free, m136).
// Next-iter global loads issued before barrier 1 so they overlap compute.
// grid = (128 M-tiles, 6): blockIdx.y 0-1 -> Wk, 2-3 -> Wv, 4-5 -> Wq.
// ---------------------------------------------------------------------------
__global__ __launch_bounds__(256) void proj_gemm_mfma(
    const float* __restrict__ x,
    const float* __restrict__ Wk, const float* __restrict__ Wv,
    const float* __restrict__ Wq,
    float* __restrict__ ok, float* __restrict__ ov, float* __restrict__ oq) {
  __shared__ __align__(16) f16 Al[128 * BK];
  __shared__ __align__(16) f16 Bl[128 * BK];

  const int tid  = threadIdx.x;
  const int lane = tid & 63;
  const int w    = tid >> 6;
  const int wm   = w >> 1, wn = w & 1;   // 2x2 wave grid
  const int lr   = lane & 15;
  const int lq   = lane >> 4;

  const int mb  = blockIdx.x * 128;
  const int mat = blockIdx.y >> 1;
  const int nb  = (blockIdx.y & 1) * 128;

  const float* W = (mat == 0) ? Wk : (mat == 1) ? Wv : Wq;
  float*       C = (mat == 0) ? ok : (mat == 1) ? ov : oq;

  // staging: thread owns row srow, 32-col half (scol); 4 swizzled 16B slots
  const int srow  = tid >> 1;
  const int scol  = (tid & 1) * 32;
  const int slotb = (tid & 1) * 4;
  const int rowx  = srow & 7;
  const float* a_src = x + (size_t)(mb + srow) * D_DIM + scol;
  const float* b_src = W + (size_t)(nb + srow) * D_DIM + scol;
  f16* a_dst = Al + srow * BK;
  f16* b_dst = Bl + srow * BK;

  f32x4 acc[4][4];
  #pragma unroll
  for (int i = 0; i < 4; ++i)
    #pragma unroll
    for (int j = 0; j < 4; ++j) acc[i][j] = (f32x4){0.f, 0.f, 0.f, 0.f};

  for (int kt = 0; kt < D_DIM; kt += BK) {
    float4 av[8], bv[8];
    #pragma unroll
    for (int m = 0; m < 8; ++m) {
      av[m] = *reinterpret_cast<const float4*>(a_src + kt + 4 * m);
      bv[m] = *reinterpret_cast<const float4*>(b_src + kt + 4 * m);
    }
    __syncthreads();   // previous iter's frag reads done
    #pragma unroll
    for (int j = 0; j < 4; ++j) {
      const int sa = ((slotb + j) ^ rowx) * 8;
      *(f16x8*)&a_dst[sa] = cvt8(av[2 * j], av[2 * j + 1]);
      *(f16x8*)&b_dst[sa] = cvt8(bv[2 * j], bv[2 * j + 1]);
    }
    __syncthreads();
    #pragma unroll
    for (int kk = 0; kk < 2; ++kk) {
      f16x8 af[4], bf[4];
      #pragma unroll
      for (int mi = 0; mi < 4; ++mi) {
        const int row = 64 * wm + 16 * mi + lr;
        const int sl  = (4 * kk + lq) ^ (row & 7);
        af[mi] = *(const f16x8*)&Al[row * BK + sl * 8];
      }
      #pragma unroll
      for (int nj = 0; nj < 4; ++nj) {
        const int row = 64 * wn + 16 * nj + lr;
        const int sl  = (4 * kk + lq) ^ (row & 7);
        bf[nj] = *(const f16x8*)&Bl[row * BK + sl * 8];
      }
      #pragma unroll
      for (int mi = 0; mi < 4; ++mi)
        #pragma unroll
        for (int nj = 0; nj < 4; ++nj)
          acc[mi][nj] = __builtin_amdgcn_mfma_f32_16x16x32_f16(af[mi], bf[nj], acc[mi][nj], 0, 0, 0);
    }
  }

  // epilogue: C/D layout col = lane&15, row = (lane>>4)*4 + r
  #pragma unroll
  for (int mi = 0; mi < 4; ++mi)
    #pragma unroll
    for (int nj = 0; nj < 4; ++nj)
      #pragma unroll
      for (int r = 0; r < 4; ++r) {
        const int rg = mb + 64 * wm + 16 * mi + 4 * lq + r;
        const int cg = nb + 64 * wn + 16 * nj + lr;
        C[(size_t)rg * N_DIM + cg] = acc[mi][nj][r];
      }
}

// ---------------------------------------------------------------------------
// Kernel 2: k-row L2 normalize (unchanged).
// ---------------------------------------------------------------------------
__global__ __launch_bounds__(256) void knorm_kernel(float* __restrict__ k) {
  const int w    = threadIdx.x >> 6;
  const int lane = threadIdx.x & 63;
  const int row  = blockIdx.x * 4 + w;
  float* p = k + (size_t)row * N_DIM + lane * 4;
  float4 f = *reinterpret_cast<const float4*>(p);
  float ss = f.x * f.x + f.y * f.y + f.z * f.z + f.w * f.w;
  #pragma unroll
  for (int m = 1; m < 64; m <<= 1) ss += __shfl_xor(ss, m, 64);
  const float inv = 1.0f / (sqrtf(ss) + 1e-6f);
  f.x *= inv; f.y *= inv; f.z *= inv; f.w *= inv;
  *reinterpret_cast<float4*>(p) = f;
}

// ---------------------------------------------------------------------------
// Kernel 3: per-(batch,chunk) WY factors (unchanged).
//   A = stril(K K^T) fp32; W = (I+A)^{-1}; G = tril(Q K^T) -> fp16 ws.
// ---------------------------------------------------------------------------
__global__ __launch_bounds__(256, 2) void precompute_wg(
    const float* __restrict__ kn, const float* __restrict__ q,
    f16* __restrict__ Wg, f16* __restrict__ Gg) {
  __shared__ __align__(16) f16 Kh[32 * LDK];
  __shared__ __align__(16) f16 Qh[32 * LDK];
  __shared__ float Al[32 * 33];

  const int tid  = threadIdx.x;
  const int lane = tid & 63;
  const int w    = tid >> 6;
  const int lr   = lane & 15;
  const int lq   = lane >> 4;
  const int tm   = w >> 1, tn = w & 1;
  const int b    = blockIdx.x >> 4;
  const int c    = blockIdx.x & 15;
  const int t0g  = c * CHUNK;

  {
    const int t = tid >> 3, cg = tid & 7;
    const float* ks = kn + (size_t)(t0g + t) * ST + b * N_DIM + cg * 32;
    const float* qs = q  + (size_t)(t0g + t) * ST + b * N_DIM + cg * 32;
    #pragma unroll
    for (int m = 0; m < 4; ++m) {
      float4 f0 = *(const float4*)(ks + 8 * m);
      float4 f1 = *(const float4*)(ks + 8 * m + 4);
      *(f16x8*)&Kh[t * LDK + cg * 32 + 8 * m] = cvt8(f0, f1);
      float4 g0 = *(const float4*)(qs + 8 * m);
      float4 g1 = *(const float4*)(qs + 8 * m + 4);
      *(f16x8*)&Qh[t * LDK + cg * 32 + 8 * m] = cvt8(g0, g1);
    }
  }
  __syncthreads();

  f32x4 Aa = {0.f, 0.f, 0.f, 0.f}, Ga = {0.f, 0.f, 0.f, 0.f};
  #pragma unroll
  for (int kk = 0; kk < 8; ++kk) {
    f16x8 ka = *(const f16x8*)&Kh[(16 * tm + lr) * LDK + 32 * kk + 8 * lq];
    f16x8 qa = *(const f16x8*)&Qh[(16 * tm + lr) * LDK + 32 * kk + 8 * lq];
    f16x8 kb = *(const f16x8*)&Kh[(16 * tn + lr) * LDK + 32 * kk + 8 * lq];
    Aa = __builtin_amdgcn_mfma_f32_16x16x32_f16(ka, kb, Aa, 0, 0, 0);
    Ga = __builtin_amdgcn_mfma_f32_16x16x32_f16(qa, kb, Ga, 0, 0, 0);
  }
  {
    const int s = 16 * tn + lr;
    f16* gdst = Gg + (size_t)blockIdx.x * 1280;
    #pragma unroll
    for (int r = 0; r < 4; ++r) {
      const int t = 16 * tm + 4 * lq + r;
      Al[t * 33 + s] = (s < t) ? Aa[r] : 0.f;
      gdst[t * LDT + s] = (f16)((s <= t) ? Ga[r] : 0.f);
    }
  }
  __syncthreads();

  if (tid < 32) {
    float wv[32];
    f16* wdst = Wg + (size_t)blockIdx.x * 1280;
    #pragma unroll
    for (int t = 0; t < 32; ++t) {
      float s0 = 0.f, s1 = 0.f, s2 = 0.f, s3 = 0.f;
      #pragma unroll
      for (int s = 0; s < 32; ++s) {
        if (s >= t) break;
        const float a = Al[t * 33 + s];
        if ((s & 3) == 0) s0 = fmaf(a, wv[s], s0);
        else if ((s & 3) == 1) s1 = fmaf(a, wv[s], s1);
        else if ((s & 3) == 2) s2 = fmaf(a, wv[s], s2);
        else s3 = fmaf(a, wv[s], s3);
      }
      wv[t] = ((t == tid) ? 1.f : 0.f) - ((s0 + s1) + (s2 + s3));
    }
    #pragma unroll
    for (int t = 0; t < 32; ++t) wdst[t * LDT + tid] = (f16)wv[t];
  }
}

// ---------------------------------------------------------------------------
// Kernel 4: chunked delta-rule scan (unchanged).
// ---------------------------------------------------------------------------
__global__ __launch_bounds__(256, 1) void scan_chunked(
    const float* __restrict__ kn, const float* __restrict__ v,
    const float* __restrict__ q, const float* __restrict__ S0,
    const f16* __restrict__ Wg, const f16* __restrict__ Gg,
    float* __restrict__ out) {
  __shared__ __align__(16) f16 Kh[32 * LDK];
  __shared__ __align__(16) f16 Qh[32 * LDK];
  __shared__ __align__(16) f16 Sh[32 * LDK];
  __shared__ __align__(16) f16 KhT[256 * LDT];
  __shared__ __align__(16) f16 Wl[32 * LDT];
  __shared__ __align__(16) f16 Gl[32 * LDT];
  __shared__ __align__(16) f16 U0T[32 * LDT];
  __shared__ __align__(16) f16 UT[32 * LDT];
  __shared__ __align__(16) float Vl[32 * LDV];

  const int tid  = threadIdx.x;
  const int lane = tid & 63;
  const int w    = tid >> 6;
  const int lr   = lane & 15;
  const int lq   = lane >> 4;
  const int tm   = w >> 1, tn = w & 1;
  const int b    = blockIdx.x & 31;
  const int i0   = (blockIdx.x >> 5) * IBLK;

  f32x4 acc[2][4];
  const float* S0b = S0 + (size_t)b * N_DIM * N_DIM + (size_t)i0 * N_DIM;
  #pragma unroll
  for (int ti = 0; ti < 2; ++ti)
    #pragma unroll
    for (int jt = 0; jt < 4; ++jt)
      #pragma unroll
      for (int r = 0; r < 4; ++r) {
        const int i = 16 * ti + 4 * lq + r;
        const int j = 64 * w + 16 * jt + lr;
        acc[ti][jt][r] = S0b[(size_t)i * N_DIM + j];
      }
  {
    const int i = tid >> 3, cg = tid & 7;
    const float* ss = S0b + (size_t)i * N_DIM + cg * 32;
    #pragma unroll
    for (int m = 0; m < 4; ++m) {
      float4 f0 = *(const float4*)(ss + 8 * m);
      float4 f1 = *(const float4*)(ss + 8 * m + 4);
      *(f16x8*)&Sh[i * LDK + cg * 32 + 8 * m] = cvt8(f0, f1);
    }
  }
  __syncthreads();

  for (int c = 0; c < NCHUNK; ++c) {
    const int t0g = c * CHUNK;
    {
      const int t = tid >> 3, cg = tid & 7;
      const float* ks = kn + (size_t)(t0g + t) * ST + b * N_DIM + cg * 32;
      const float* qs = q  + (size_t)(t0g + t) * ST + b * N_DIM + cg * 32;
      #pragma unroll
      for (int m = 0; m < 4; ++m) {
        float4 f0 = *(const float4*)(ks + 8 * m);
        float4 f1 = *(const float4*)(ks + 8 * m + 4);
        *(f16x8*)&Kh[t * LDK + cg * 32 + 8 * m] = cvt8(f0, f1);
        float4 g0 = *(const float4*)(qs + 8 * m);
        float4 g1 = *(const float4*)(qs + 8 * m + 4);
        *(f16x8*)&Qh[t * LDK + cg * 32 + 8 * m] = cvt8(g0, g1);
      }
      float4 vf = *(const float4*)(v + (size_t)(t0g + t) * ST + b * N_DIM + i0 + cg * 4);
      *(float4*)&Vl[t * LDV + cg * 4] = vf;
    }
    {
      const float* col = kn + (size_t)t0g * ST + b * N_DIM + tid;
      #pragma unroll
      for (int m = 0; m < 4; ++m) {
        f16x8 h;
        #pragma unroll
        for (int e = 0; e < 8; ++e) h[e] = (f16)col[(size_t)(8 * m + e) * ST];
        *(f16x8*)&KhT[tid * LDT + 8 * m] = h;
      }
    }
    if (tid < 160) {
      const f16x8* wsrc = (const f16x8*)(Wg + (size_t)(b * NCHUNK + c) * 1280);
      const f16x8* gsrc = (const f16x8*)(Gg + (size_t)(b * NCHUNK + c) * 1280);
      ((f16x8*)Wl)[tid] = wsrc[tid];
      ((f16x8*)Gl)[tid] = gsrc[tid];
    }
    __syncthreads();

    f32x4 Pacc = {0.f, 0.f, 0.f, 0.f};
    f32x4 Oq   = {0.f, 0.f, 0.f, 0.f};
    #pragma unroll
    for (int kk = 0; kk < 8; ++kk) {
      f16x8 ka = *(const f16x8*)&Kh[(16 * tm + lr) * LDK + 32 * kk + 8 * lq];
      f16x8 qa = *(const f16x8*)&Qh[(16 * tm + lr) * LDK + 32 * kk + 8 * lq];
      f16x8 sb = *(const f16x8*)&Sh[(16 * tn + lr) * LDK + 32 * kk + 8 * lq];
      Pacc = __builtin_amdgcn_mfma_f32_16x16x32_f16(ka, sb, Pacc, 0, 0, 0);
      Oq   = __builtin_amdgcn_mfma_f32_16x16x32_f16(qa, sb, Oq,   0, 0, 0);
    }
    {
      const int i = 16 * tn + lr;
      const int t0 = 16 * tm + 4 * lq;
      f16x4 u0;
      #pragma unroll
      for (int r = 0; r < 4; ++r) u0[r] = (f16)(Vl[(t0 + r) * LDV + i] - Pacc[r]);
      *(f16x4*)&U0T[i * LDT + t0] = u0;
    }
    __syncthreads();

    {
      f16x8 wa = *(const f16x8*)&Wl[(16 * tm + lr) * LDT + 8 * lq];
      f16x8 ub = *(const f16x8*)&U0T[(16 * tn + lr) * LDT + 8 * lq];
      f32x4 z = {0.f, 0.f, 0.f, 0.f};
      f32x4 Ud = __builtin_amdgcn_mfma_f32_16x16x32_f16(wa, ub, z, 0, 0, 0);
      const int i = 16 * tn + lr;
      const int t0 = 16 * tm + 4 * lq;
      f16x4 uh;
      #pragma unroll
      for (int r = 0; r < 4; ++r) uh[r] = (f16)Ud[r];
      *(f16x4*)&UT[i * LDT + t0] = uh;
    }
    __syncthreads();

    {
      f16x8 ga = *(const f16x8*)&Gl[(16 * tm + lr) * LDT + 8 * lq];
      f16x8 ub = *(const f16x8*)&UT[(16 * tn + lr) * LDT + 8 * lq];
      f32x4 O = __builtin_amdgcn_mfma_f32_16x16x32_f16(ga, ub, Oq, 0, 0, 0);
      const int i = 16 * tn + lr;
      const int tt0 = 16 * tm + 4 * lq;
      #pragma unroll
      for (int r = 0; r < 4; ++r) {
        const float sq = O[r];
        const float sig = 1.0f / (1.0f + __expf(-sq));
        out[(size_t)(t0g + tt0 + r) * ST + b * N_DIM + i0 + i] = sq * sq * sig;
      }
    }
    #pragma unroll
    for (int ti = 0; ti < 2; ++ti) {
      f16x8 ua = *(const f16x8*)&UT[(16 * ti + lr) * LDT + 8 * lq];
      #pragma unroll
      for (int jt = 0; jt < 4; ++jt) {
        f16x8 kb = *(const f16x8*)&KhT[(64 * w + 16 * jt + lr) * LDT + 8 * lq];
        acc[ti][jt] = __builtin_amdgcn_mfma_f32_16x16x32_f16(ua, kb, acc[ti][jt], 0, 0, 0);
      }
    }
    #pragma unroll
    for (int ti = 0; ti < 2; ++ti)
      #pragma unroll
      for (int jt = 0; jt < 4; ++jt)
        #pragma unroll
        for (int r = 0; r < 4; ++r)
          Sh[(16 * ti + 4 * lq + r) * LDK + 64 * w + 16 * jt + lr] = (f16)acc[ti][jt][r];
    __syncthreads();
  }
}

// ---------------------------------------------------------------------------
extern "C" void kernel_launch(void* const* d_in, const int* in_sizes, int n_in,
                              void* d_out, int out_size, void* d_ws, size_t ws_size,
                              hipStream_t stream) {
  (void)in_sizes; (void)n_in; (void)out_size; (void)ws_size;
  const float* x  = (const float*)d_in[0];
  const float* S0 = (const float*)d_in[1];
  const float* Wk = (const float*)d_in[2];
  const float* Wv = (const float*)d_in[3];
  const float* Wq = (const float*)d_in[4];
  float* outp = (float*)d_out;

  float* kn = (float*)d_ws;
  float* vv = kn + (size_t)M_DIM * N_DIM;
  float* qq = vv + (size_t)M_DIM * N_DIM;
  f16*   Wg = (f16*)(qq + (size_t)M_DIM * N_DIM);
  f16*   Gg = Wg + (size_t)B_DIM * NCHUNK * 1280;

  dim3 gg(M_DIM / 128, 6);
  proj_gemm_mfma<<<gg, 256, 0, stream>>>(x, Wk, Wv, Wq, kn, vv, qq);
  knorm_kernel<<<M_DIM / 4, 256, 0, stream>>>(kn);
  precompute_wg<<<B_DIM * NCHUNK, 256, 0, stream>>>(kn, qq, Wg, Gg);
  scan_chunked<<<B_DIM * (N_DIM / IBLK), 256, 0, stream>>>(kn, vv, qq, S0, Wg, Gg, outp);
}

// Round 5
// 173.979 us; speedup vs baseline: 4.8163x; 1.2166x over previous
//
#include <hip/hip_runtime.h>
#include <hip/hip_bf16.h>
#include <math.h>

#define T_DIM 512
#define B_DIM 32
#define D_DIM 1024
#define N_DIM 256
#define M_DIM (T_DIM * B_DIM)
#define CHUNK 32
#define NCHUNK (T_DIM / CHUNK)   // 16
#define IBLK 32
#define ST (B_DIM * N_DIM)       // 8192 elems: t-stride in kn/v/q/out
#define BK 64                    // GEMM K-tile (f16)

typedef _Float16 f16;
typedef _Float16 f16x8 __attribute__((ext_vector_type(8)));
typedef _Float16 f16x4 __attribute__((ext_vector_type(4)));
typedef float    f32x4 __attribute__((ext_vector_type(4)));

#define LDK 264   // halves/row for Kh/Qh/Sh (33 quads of 16B - odd -> conflict-free)
#define LDT 40    // halves/row for KhT/W/G/U0T/UT (5 quads - odd)
#define LDV 36    // floats/row for Vl (9 quads - odd)

__device__ __forceinline__ f16x8 cvt8(const float4& a, const float4& b) {
  f16x8 h;
  h[0] = (f16)a.x; h[1] = (f16)a.y; h[2] = (f16)a.z; h[3] = (f16)a.w;
  h[4] = (f16)b.x; h[5] = (f16)b.y; h[6] = (f16)b.z; h[7] = (f16)b.w;
  return h;
}

// ---------------------------------------------------------------------------
// Kernel 1 (round-5): f16 MFMA projection GEMM, latency-pipelined.
// Round-4 diagnosis: MfmaUtil 7.6%, VALUBusy 14%, Occ 19% -> global-load
// latency fully exposed each K-iter (loads consumed immediately).
// Fixes: (a) reg-prefetch of iter k+1 issued BEFORE the MFMA phase of iter k
// (cvt + LDS write after MFMA -> ~full MFMA phase hides the latency);
// (b) double-buffered LDS with ONE barrier per iter (read cur / write cur^1
// are disjoint); (c) outputs stored f16 (halves write + downstream reads).
// Swizzle unchanged (round 4 measured 0 bank conflicts).
// ---------------------------------------------------------------------------
__global__ __launch_bounds__(256) void proj_gemm_mfma(
    const float* __restrict__ x,
    const float* __restrict__ Wk, const float* __restrict__ Wv,
    const float* __restrict__ Wq,
    f16* __restrict__ ok, f16* __restrict__ ov, f16* __restrict__ oq) {
  __shared__ __align__(16) f16 Al[2 * 128 * BK];
  __shared__ __align__(16) f16 Bl[2 * 128 * BK];

  const int tid  = threadIdx.x;
  const int lane = tid & 63;
  const int w    = tid >> 6;
  const int wm   = w >> 1, wn = w & 1;   // 2x2 wave grid
  const int lr   = lane & 15;
  const int lq   = lane >> 4;

  const int mb  = blockIdx.x * 128;
  const int mat = blockIdx.y >> 1;
  const int nb  = (blockIdx.y & 1) * 128;

  const float* W = (mat == 0) ? Wk : (mat == 1) ? Wv : Wq;
  f16*         C = (mat == 0) ? ok : (mat == 1) ? ov : oq;

  const int srow  = tid >> 1;
  const int scol  = (tid & 1) * 32;
  const int slotb = (tid & 1) * 4;
  const int rowx  = srow & 7;
  const float* a_src = x + (size_t)(mb + srow) * D_DIM + scol;
  const float* b_src = W + (size_t)(nb + srow) * D_DIM + scol;

  f32x4 acc[4][4];
  #pragma unroll
  for (int i = 0; i < 4; ++i)
    #pragma unroll
    for (int j = 0; j < 4; ++j) acc[i][j] = (f32x4){0.f, 0.f, 0.f, 0.f};

  float4 av[8], bv[8];
  // prologue: load + stage K-tile 0 into buffer 0
  #pragma unroll
  for (int m = 0; m < 8; ++m) {
    av[m] = *reinterpret_cast<const float4*>(a_src + 4 * m);
    bv[m] = *reinterpret_cast<const float4*>(b_src + 4 * m);
  }
  #pragma unroll
  for (int j = 0; j < 4; ++j) {
    const int sa = ((slotb + j) ^ rowx) * 8;
    *(f16x8*)&Al[srow * BK + sa] = cvt8(av[2 * j], av[2 * j + 1]);
    *(f16x8*)&Bl[srow * BK + sa] = cvt8(bv[2 * j], bv[2 * j + 1]);
  }
  __syncthreads();

  int cur = 0;
  for (int kt = 0; kt < D_DIM; kt += BK) {
    const bool more = (kt + BK) < D_DIM;
    // issue next tile's loads now; they land during the MFMA phase
    if (more) {
      #pragma unroll
      for (int m = 0; m < 8; ++m) {
        av[m] = *reinterpret_cast<const float4*>(a_src + kt + BK + 4 * m);
        bv[m] = *reinterpret_cast<const float4*>(b_src + kt + BK + 4 * m);
      }
    }
    const f16* Ab = Al + cur * (128 * BK);
    const f16* Bb = Bl + cur * (128 * BK);
    #pragma unroll
    for (int kk = 0; kk < 2; ++kk) {
      f16x8 af[4], bf[4];
      #pragma unroll
      for (int mi = 0; mi < 4; ++mi) {
        const int row = 64 * wm + 16 * mi + lr;
        const int sl  = (4 * kk + lq) ^ (row & 7);
        af[mi] = *(const f16x8*)&Ab[row * BK + sl * 8];
      }
      #pragma unroll
      for (int nj = 0; nj < 4; ++nj) {
        const int row = 64 * wn + 16 * nj + lr;
        const int sl  = (4 * kk + lq) ^ (row & 7);
        bf[nj] = *(const f16x8*)&Bb[row * BK + sl * 8];
      }
      #pragma unroll
      for (int mi = 0; mi < 4; ++mi)
        #pragma unroll
        for (int nj = 0; nj < 4; ++nj)
          acc[mi][nj] = __builtin_amdgcn_mfma_f32_16x16x32_f16(af[mi], bf[nj], acc[mi][nj], 0, 0, 0);
    }
    // cvt + stage into the OTHER buffer (disjoint from current reads)
    if (more) {
      f16* Aw = Al + (cur ^ 1) * (128 * BK);
      f16* Bw = Bl + (cur ^ 1) * (128 * BK);
      #pragma unroll
      for (int j = 0; j < 4; ++j) {
        const int sa = ((slotb + j) ^ rowx) * 8;
        *(f16x8*)&Aw[srow * BK + sa] = cvt8(av[2 * j], av[2 * j + 1]);
        *(f16x8*)&Bw[srow * BK + sa] = cvt8(bv[2 * j], bv[2 * j + 1]);
      }
    }
    __syncthreads();
    cur ^= 1;
  }

  // epilogue: C/D layout col = lane&15, row = (lane>>4)*4 + r ; store f16
  #pragma unroll
  for (int mi = 0; mi < 4; ++mi)
    #pragma unroll
    for (int nj = 0; nj < 4; ++nj)
      #pragma unroll
      for (int r = 0; r < 4; ++r) {
        const int rg = mb + 64 * wm + 16 * mi + 4 * lq + r;
        const int cg = nb + 64 * wn + 16 * nj + lr;
        C[(size_t)rg * N_DIM + cg] = (f16)acc[mi][nj][r];
      }
}

// ---------------------------------------------------------------------------
// Kernel 2: k-row L2 normalize in place, f16 storage (fp32 math).
// ---------------------------------------------------------------------------
__global__ __launch_bounds__(256) void knorm_kernel(f16* __restrict__ k) {
  const int w    = threadIdx.x >> 6;
  const int lane = threadIdx.x & 63;
  const int row  = blockIdx.x * 4 + w;
  f16* p = k + (size_t)row * N_DIM + lane * 4;
  f16x4 h = *reinterpret_cast<const f16x4*>(p);
  const float x0 = (float)h[0], x1 = (float)h[1], x2 = (float)h[2], x3 = (float)h[3];
  float ss = x0 * x0 + x1 * x1 + x2 * x2 + x3 * x3;
  #pragma unroll
  for (int m = 1; m < 64; m <<= 1) ss += __shfl_xor(ss, m, 64);
  const float inv = 1.0f / (sqrtf(ss) + 1e-6f);
  h[0] = (f16)(x0 * inv); h[1] = (f16)(x1 * inv);
  h[2] = (f16)(x2 * inv); h[3] = (f16)(x3 * inv);
  *reinterpret_cast<f16x4*>(p) = h;
}

// ---------------------------------------------------------------------------
// Kernel 3: per-(batch,chunk) WY factors (staging now pure f16 copies).
//   A = stril(K K^T) fp32; W = (I+A)^{-1}; G = tril(Q K^T) -> fp16 ws.
// ---------------------------------------------------------------------------
__global__ __launch_bounds__(256, 2) void precompute_wg(
    const f16* __restrict__ kn, const f16* __restrict__ q,
    f16* __restrict__ Wg, f16* __restrict__ Gg) {
  __shared__ __align__(16) f16 Kh[32 * LDK];
  __shared__ __align__(16) f16 Qh[32 * LDK];
  __shared__ float Al[32 * 33];

  const int tid  = threadIdx.x;
  const int lane = tid & 63;
  const int w    = tid >> 6;
  const int lr   = lane & 15;
  const int lq   = lane >> 4;
  const int tm   = w >> 1, tn = w & 1;
  const int b    = blockIdx.x >> 4;
  const int c    = blockIdx.x & 15;
  const int t0g  = c * CHUNK;

  {
    const int t = tid >> 3, cg = tid & 7;
    const f16* ks = kn + (size_t)(t0g + t) * ST + b * N_DIM + cg * 32;
    const f16* qs = q  + (size_t)(t0g + t) * ST + b * N_DIM + cg * 32;
    #pragma unroll
    for (int m = 0; m < 4; ++m) {
      *(f16x8*)&Kh[t * LDK + cg * 32 + 8 * m] = ((const f16x8*)ks)[m];
      *(f16x8*)&Qh[t * LDK + cg * 32 + 8 * m] = ((const f16x8*)qs)[m];
    }
  }
  __syncthreads();

  f32x4 Aa = {0.f, 0.f, 0.f, 0.f}, Ga = {0.f, 0.f, 0.f, 0.f};
  #pragma unroll
  for (int kk = 0; kk < 8; ++kk) {
    f16x8 ka = *(const f16x8*)&Kh[(16 * tm + lr) * LDK + 32 * kk + 8 * lq];
    f16x8 qa = *(const f16x8*)&Qh[(16 * tm + lr) * LDK + 32 * kk + 8 * lq];
    f16x8 kb = *(const f16x8*)&Kh[(16 * tn + lr) * LDK + 32 * kk + 8 * lq];
    Aa = __builtin_amdgcn_mfma_f32_16x16x32_f16(ka, kb, Aa, 0, 0, 0);
    Ga = __builtin_amdgcn_mfma_f32_16x16x32_f16(qa, kb, Ga, 0, 0, 0);
  }
  {
    const int s = 16 * tn + lr;
    f16* gdst = Gg + (size_t)blockIdx.x * 1280;
    #pragma unroll
    for (int r = 0; r < 4; ++r) {
      const int t = 16 * tm + 4 * lq + r;
      Al[t * 33 + s] = (s < t) ? Aa[r] : 0.f;
      gdst[t * LDT + s] = (f16)((s <= t) ? Ga[r] : 0.f);
    }
  }
  __syncthreads();

  if (tid < 32) {
    float wv[32];
    f16* wdst = Wg + (size_t)blockIdx.x * 1280;
    #pragma unroll
    for (int t = 0; t < 32; ++t) {
      float s0 = 0.f, s1 = 0.f, s2 = 0.f, s3 = 0.f;
      #pragma unroll
      for (int s = 0; s < 32; ++s) {
        if (s >= t) break;
        const float a = Al[t * 33 + s];
        if ((s & 3) == 0) s0 = fmaf(a, wv[s], s0);
        else if ((s & 3) == 1) s1 = fmaf(a, wv[s], s1);
        else if ((s & 3) == 2) s2 = fmaf(a, wv[s], s2);
        else s3 = fmaf(a, wv[s], s3);
      }
      wv[t] = ((t == tid) ? 1.f : 0.f) - ((s0 + s1) + (s2 + s3));
    }
    #pragma unroll
    for (int t = 0; t < 32; ++t) wdst[t * LDT + tid] = (f16)wv[t];
  }
}

// ---------------------------------------------------------------------------
// Kernel 4: chunked delta-rule scan (f16 global operands; logic unchanged).
// ---------------------------------------------------------------------------
__global__ __launch_bounds__(256, 1) void scan_chunked(
    const f16* __restrict__ kn, const f16* __restrict__ v,
    const f16* __restrict__ q, const float* __restrict__ S0,
    const f16* __restrict__ Wg, const f16* __restrict__ Gg,
    float* __restrict__ out) {
  __shared__ __align__(16) f16 Kh[32 * LDK];
  __shared__ __align__(16) f16 Qh[32 * LDK];
  __shared__ __align__(16) f16 Sh[32 * LDK];
  __shared__ __align__(16) f16 KhT[256 * LDT];
  __shared__ __align__(16) f16 Wl[32 * LDT];
  __shared__ __align__(16) f16 Gl[32 * LDT];
  __shared__ __align__(16) f16 U0T[32 * LDT];
  __shared__ __align__(16) f16 UT[32 * LDT];
  __shared__ __align__(16) float Vl[32 * LDV];

  const int tid  = threadIdx.x;
  const int lane = tid & 63;
  const int w    = tid >> 6;
  const int lr   = lane & 15;
  const int lq   = lane >> 4;
  const int tm   = w >> 1, tn = w & 1;
  const int b    = blockIdx.x & 31;
  const int i0   = (blockIdx.x >> 5) * IBLK;

  f32x4 acc[2][4];
  const float* S0b = S0 + (size_t)b * N_DIM * N_DIM + (size_t)i0 * N_DIM;
  #pragma unroll
  for (int ti = 0; ti < 2; ++ti)
    #pragma unroll
    for (int jt = 0; jt < 4; ++jt)
      #pragma unroll
      for (int r = 0; r < 4; ++r) {
        const int i = 16 * ti + 4 * lq + r;
        const int j = 64 * w + 16 * jt + lr;
        acc[ti][jt][r] = S0b[(size_t)i * N_DIM + j];
      }
  {
    const int i = tid >> 3, cg = tid & 7;
    const float* ss = S0b + (size_t)i * N_DIM + cg * 32;
    #pragma unroll
    for (int m = 0; m < 4; ++m) {
      float4 f0 = *(const float4*)(ss + 8 * m);
      float4 f1 = *(const float4*)(ss + 8 * m + 4);
      *(f16x8*)&Sh[i * LDK + cg * 32 + 8 * m] = cvt8(f0, f1);
    }
  }
  __syncthreads();

  for (int c = 0; c < NCHUNK; ++c) {
    const int t0g = c * CHUNK;
    {
      const int t = tid >> 3, cg = tid & 7;
      const f16* ks = kn + (size_t)(t0g + t) * ST + b * N_DIM + cg * 32;
      const f16* qs = q  + (size_t)(t0g + t) * ST + b * N_DIM + cg * 32;
      #pragma unroll
      for (int m = 0; m < 4; ++m) {
        *(f16x8*)&Kh[t * LDK + cg * 32 + 8 * m] = ((const f16x8*)ks)[m];
        *(f16x8*)&Qh[t * LDK + cg * 32 + 8 * m] = ((const f16x8*)qs)[m];
      }
      const f16x4 vf = *(const f16x4*)(v + (size_t)(t0g + t) * ST + b * N_DIM + i0 + cg * 4);
      *(float4*)&Vl[t * LDV + cg * 4] =
          make_float4((float)vf[0], (float)vf[1], (float)vf[2], (float)vf[3]);
    }
    {
      const f16* col = kn + (size_t)t0g * ST + b * N_DIM + tid;
      #pragma unroll
      for (int m = 0; m < 4; ++m) {
        f16x8 h;
        #pragma unroll
        for (int e = 0; e < 8; ++e) h[e] = col[(size_t)(8 * m + e) * ST];
        *(f16x8*)&KhT[tid * LDT + 8 * m] = h;
      }
    }
    if (tid < 160) {
      const f16x8* wsrc = (const f16x8*)(Wg + (size_t)(b * NCHUNK + c) * 1280);
      const f16x8* gsrc = (const f16x8*)(Gg + (size_t)(b * NCHUNK + c) * 1280);
      ((f16x8*)Wl)[tid] = wsrc[tid];
      ((f16x8*)Gl)[tid] = gsrc[tid];
    }
    __syncthreads();

    f32x4 Pacc = {0.f, 0.f, 0.f, 0.f};
    f32x4 Oq   = {0.f, 0.f, 0.f, 0.f};
    #pragma unroll
    for (int kk = 0; kk < 8; ++kk) {
      f16x8 ka = *(const f16x8*)&Kh[(16 * tm + lr) * LDK + 32 * kk + 8 * lq];
      f16x8 qa = *(const f16x8*)&Qh[(16 * tm + lr) * LDK + 32 * kk + 8 * lq];
      f16x8 sb = *(const f16x8*)&Sh[(16 * tn + lr) * LDK + 32 * kk + 8 * lq];
      Pacc = __builtin_amdgcn_mfma_f32_16x16x32_f16(ka, sb, Pacc, 0, 0, 0);
      Oq   = __builtin_amdgcn_mfma_f32_16x16x32_f16(qa, sb, Oq,   0, 0, 0);
    }
    {
      const int i = 16 * tn + lr;
      const int t0 = 16 * tm + 4 * lq;
      f16x4 u0;
      #pragma unroll
      for (int r = 0; r < 4; ++r) u0[r] = (f16)(Vl[(t0 + r) * LDV + i] - Pacc[r]);
      *(f16x4*)&U0T[i * LDT + t0] = u0;
    }
    __syncthreads();

    {
      f16x8 wa = *(const f16x8*)&Wl[(16 * tm + lr) * LDT + 8 * lq];
      f16x8 ub = *(const f16x8*)&U0T[(16 * tn + lr) * LDT + 8 * lq];
      f32x4 z = {0.f, 0.f, 0.f, 0.f};
      f32x4 Ud = __builtin_amdgcn_mfma_f32_16x16x32_f16(wa, ub, z, 0, 0, 0);
      const int i = 16 * tn + lr;
      const int t0 = 16 * tm + 4 * lq;
      f16x4 uh;
      #pragma unroll
      for (int r = 0; r < 4; ++r) uh[r] = (f16)Ud[r];
      *(f16x4*)&UT[i * LDT + t0] = uh;
    }
    __syncthreads();

    {
      f16x8 ga = *(const f16x8*)&Gl[(16 * tm + lr) * LDT + 8 * lq];
      f16x8 ub = *(const f16x8*)&UT[(16 * tn + lr) * LDT + 8 * lq];
      f32x4 O = __builtin_amdgcn_mfma_f32_16x16x32_f16(ga, ub, Oq, 0, 0, 0);
      const int i = 16 * tn + lr;
      const int tt0 = 16 * tm + 4 * lq;
      #pragma unroll
      for (int r = 0; r < 4; ++r) {
        const float sq = O[r];
        const float sig = 1.0f / (1.0f + __expf(-sq));
        out[(size_t)(t0g + tt0 + r) * ST + b * N_DIM + i0 + i] = sq * sq * sig;
      }
    }
    #pragma unroll
    for (int ti = 0; ti < 2; ++ti) {
      f16x8 ua = *(const f16x8*)&UT[(16 * ti + lr) * LDT + 8 * lq];
      #pragma unroll
      for (int jt = 0; jt < 4; ++jt) {
        f16x8 kb = *(const f16x8*)&KhT[(64 * w + 16 * jt + lr) * LDT + 8 * lq];
        acc[ti][jt] = __builtin_amdgcn_mfma_f32_16x16x32_f16(ua, kb, acc[ti][jt], 0, 0, 0);
      }
    }
    #pragma unroll
    for (int ti = 0; ti < 2; ++ti)
      #pragma unroll
      for (int jt = 0; jt < 4; ++jt)
        #pragma unroll
        for (int r = 0; r < 4; ++r)
          Sh[(16 * ti + 4 * lq + r) * LDK + 64 * w + 16 * jt + lr] = (f16)acc[ti][jt][r];
    __syncthreads();
  }
}

// ---------------------------------------------------------------------------
extern "C" void kernel_launch(void* const* d_in, const int* in_sizes, int n_in,
                              void* d_out, int out_size, void* d_ws, size_t ws_size,
                              hipStream_t stream) {
  (void)in_sizes; (void)n_in; (void)out_size; (void)ws_size;
  const float* x  = (const float*)d_in[0];
  const float* S0 = (const float*)d_in[1];
  const float* Wk = (const float*)d_in[2];
  const float* Wv = (const float*)d_in[3];
  const float* Wq = (const float*)d_in[4];
  float* outp = (float*)d_out;

  // ws: kn | v | q (f16, 3 x 8.4M) then W | G (f16, 1.31MB each)
  f16* kn = (f16*)d_ws;
  f16* vv = kn + (size_t)M_DIM * N_DIM;
  f16* qq = vv + (size_t)M_DIM * N_DIM;
  f16* Wg = qq + (size_t)M_DIM * N_DIM;
  f16* Gg = Wg + (size_t)B_DIM * NCHUNK * 1280;

  dim3 gg(M_DIM / 128, 6);
  proj_gemm_mfma<<<gg, 256, 0, stream>>>(x, Wk, Wv, Wq, kn, vv, qq);
  knorm_kernel<<<M_DIM / 4, 256, 0, stream>>>(kn);
  precompute_wg<<<B_DIM * NCHUNK, 256, 0, stream>>>(kn, qq, Wg, Gg);
  scan_chunked<<<B_DIM * (N_DIM / IBLK), 256, 0, stream>>>(kn, vv, qq, S0, Wg, Gg, outp);
}

// Round 7
// 119.112 us; speedup vs baseline: 7.0349x; 1.4606x over previous
//
#include <hip/hip_runtime.h>
#include <hip/hip_bf16.h>
#include <math.h>

#define T_DIM 512
#define B_DIM 32
#define D_DIM 1024
#define N_DIM 256
#define M_DIM (T_DIM * B_DIM)
#define CHUNK 32
#define NCHUNK (T_DIM / CHUNK)   // 16
#define IBLK 32
#define ST (B_DIM * N_DIM)       // 8192 elems: t-stride in kn/v/q/out
#define BK 64                    // GEMM K-tile

typedef _Float16 f16;
typedef _Float16 f16x8 __attribute__((ext_vector_type(8)));
typedef _Float16 f16x4 __attribute__((ext_vector_type(4)));
typedef __fp16   h16x2 __attribute__((ext_vector_type(2)));   // cvt_pkrtz return type
typedef float    f32x4 __attribute__((ext_vector_type(4)));

#define LDK 264   // halves/row for Kh/Qh/Sh (33 quads of 16B - odd -> conflict-free)
#define LDT 40    // halves/row for KhT/W/G/U0T/UT (5 quads - odd)
#define LDV 36    // floats/row for Vl (9 quads - odd)

#define GLOAD_LDS16(g, l)                                         \
  __builtin_amdgcn_global_load_lds(                               \
      (const __attribute__((address_space(1))) void*)(g),         \
      (__attribute__((address_space(3))) void*)(l), 16, 0, 0)

__device__ __forceinline__ f16x8 cvt8(const float4& a, const float4& b) {
  f16x8 h;
  h[0] = (f16)a.x; h[1] = (f16)a.y; h[2] = (f16)a.z; h[3] = (f16)a.w;
  h[4] = (f16)b.x; h[5] = (f16)b.y; h[6] = (f16)b.z; h[7] = (f16)b.w;
  return h;
}

// pack 8 fp32 -> 8 f16 via v_cvt_pkrtz (union member typed __fp16 to match
// the builtin's return vector type; bit-identical to _Float16).
__device__ __forceinline__ f16x8 pk8(const f32x4 a, const f32x4 b) {
  union { f16x8 v; h16x2 p[4]; } u;
  u.p[0] = __builtin_amdgcn_cvt_pkrtz(a[0], a[1]);
  u.p[1] = __builtin_amdgcn_cvt_pkrtz(a[2], a[3]);
  u.p[2] = __builtin_amdgcn_cvt_pkrtz(b[0], b[1]);
  u.p[3] = __builtin_amdgcn_cvt_pkrtz(b[2], b[3]);
  return u.v;
}

// ---------------------------------------------------------------------------
// Kernel 0: convert the three weight matrices fp32 -> f16 once (3 MB -> 1.5).
// ---------------------------------------------------------------------------
__global__ __launch_bounds__(256) void cvt_w_kernel(
    const float* __restrict__ wk, const float* __restrict__ wv,
    const float* __restrict__ wq, f16* __restrict__ out) {
  const int i = (blockIdx.x * 256 + threadIdx.x) * 8;
  const int m = blockIdx.y;
  const float* src = (m == 0) ? wk : (m == 1) ? wv : wq;
  const float4 f0 = *(const float4*)(src + i);
  const float4 f1 = *(const float4*)(src + i + 4);
  *(f16x8*)(out + (size_t)m * (N_DIM * D_DIM) + i) = cvt8(f0, f1);
}

// ---------------------------------------------------------------------------
// Kernel 1 (round-6/7): m97-structure f16 MFMA GEMM.
// Round-5 diagnosis: 6,250 CU-cyc/block-iter vs m97's ~1,470 — reg-staging
// round-trip + 64KB-dbuf occupancy cap + fp32 staged bytes. Fixes:
//  * global_load_lds width=16 for A and B (no VGPR round-trip; vmcnt drains
//    only at the barrier) — single-buffer, 2 barriers/iter, LDS 48 KB
//    -> 3+ blocks/CU.
//  * rule #21 swizzle: linear LDS dest, inverse-swizzled GLOBAL source,
//    swizzled ds_read (A: quad ^= row&15; B: oct ^= row&7). Both frag-read
//    patterns hit the exact wave64-b128 floor (8 words/bank) — no conflicts.
//  * A stays fp32 in LDS; f32->f16 via cvt_pkrtz at frag-read time (saves a
//    separate 96 MB convert pass over x). B (weights) pre-converted to f16.
// grid (128, 6): y-sharers of an A-panel differ by 128 in linear id
// (128 % 8 == 0) -> same XCD -> automatic L2 reuse of x panels.
// ---------------------------------------------------------------------------
__global__ __launch_bounds__(256, 4) void proj_gemm_mfma(
    const float* __restrict__ x, const f16* __restrict__ Wh,
    f16* __restrict__ ok, f16* __restrict__ ov, f16* __restrict__ oq) {
  __shared__ __align__(16) float Af[128 * BK];  // 32 KB, 16 quad-slots/row
  __shared__ __align__(16) f16   Bh[128 * BK];  // 16 KB, 8 oct-slots/row

  const int tid  = threadIdx.x;
  const int lane = tid & 63;
  const int w    = tid >> 6;
  const int wm   = w >> 1, wn = w & 1;   // 2x2 wave grid
  const int lr   = lane & 15;
  const int lq   = lane >> 4;

  const int mb  = blockIdx.x * 128;
  const int mat = blockIdx.y >> 1;
  const int nb  = (blockIdx.y & 1) * 128;

  const f16* Wmat = Wh + (size_t)mat * (N_DIM * D_DIM) + (size_t)nb * D_DIM;
  f16*       C    = (mat == 0) ? ok : (mat == 1) ? ov : oq;

  // staging geometry (per-lane source, wave-uniform LDS base)
  const int arow0 = 4 * w + (lane >> 4);   // + 16j
  const int aslot = lane & 15;             // linear dest quad-slot
  const int brow0 = 8 * w + (lane >> 3);   // + 32j
  const int bslot = lane & 7;              // linear dest oct-slot

  f32x4 acc[4][4];
  #pragma unroll
  for (int i = 0; i < 4; ++i)
    #pragma unroll
    for (int j = 0; j < 4; ++j) acc[i][j] = (f32x4){0.f, 0.f, 0.f, 0.f};

  for (int kt = 0; kt < D_DIM; kt += BK) {
    // ---- stage A (8 issues) and B (4 issues): DMA, source-swizzled
    #pragma unroll
    for (int j = 0; j < 8; ++j) {
      const int r  = 16 * j + arow0;
      const int cq = aslot ^ (r & 15);
      const float* g = x + (size_t)(mb + r) * D_DIM + kt + cq * 4;
      GLOAD_LDS16(g, &Af[(16 * j + 4 * w) * BK]);
    }
    #pragma unroll
    for (int j = 0; j < 4; ++j) {
      const int r  = 32 * j + brow0;
      const int co = bslot ^ (r & 7);
      const f16* g = Wmat + (size_t)r * D_DIM + kt + co * 8;
      GLOAD_LDS16(g, &Bh[(32 * j + 8 * w) * BK]);
    }
    __syncthreads();   // drains vmcnt(0): tiles resident

    #pragma unroll
    for (int kk = 0; kk < 2; ++kk) {
      f16x8 af[4], bf[4];
      #pragma unroll
      for (int mi = 0; mi < 4; ++mi) {
        const int row = 64 * wm + 16 * mi + lr;
        const int q0  = (8 * kk + 2 * lq)     ^ (row & 15);
        const int q1  = (8 * kk + 2 * lq + 1) ^ (row & 15);
        const f32x4 a0 = *(const f32x4*)&Af[row * BK + q0 * 4];
        const f32x4 a1 = *(const f32x4*)&Af[row * BK + q1 * 4];
        af[mi] = pk8(a0, a1);
      }
      #pragma unroll
      for (int nj = 0; nj < 4; ++nj) {
        const int row = 64 * wn + 16 * nj + lr;
        const int sp  = (4 * kk + lq) ^ (row & 7);
        bf[nj] = *(const f16x8*)&Bh[row * BK + sp * 8];
      }
      #pragma unroll
      for (int mi = 0; mi < 4; ++mi)
        #pragma unroll
        for (int nj = 0; nj < 4; ++nj)
          acc[mi][nj] = __builtin_amdgcn_mfma_f32_16x16x32_f16(af[mi], bf[nj], acc[mi][nj], 0, 0, 0);
    }
    __syncthreads();   // all reads done before next DMA overwrites
  }

  // epilogue: C/D layout col = lane&15, row = (lane>>4)*4 + r ; store f16
  #pragma unroll
  for (int mi = 0; mi < 4; ++mi)
    #pragma unroll
    for (int nj = 0; nj < 4; ++nj)
      #pragma unroll
      for (int r = 0; r < 4; ++r) {
        const int rg = mb + 64 * wm + 16 * mi + 4 * lq + r;
        const int cg = nb + 64 * wn + 16 * nj + lr;
        C[(size_t)rg * N_DIM + cg] = (f16)acc[mi][nj][r];
      }
}

// ---------------------------------------------------------------------------
// Kernel 2: k-row L2 normalize in place, f16 storage (fp32 math).
// ---------------------------------------------------------------------------
__global__ __launch_bounds__(256) void knorm_kernel(f16* __restrict__ k) {
  const int w    = threadIdx.x >> 6;
  const int lane = threadIdx.x & 63;
  const int row  = blockIdx.x * 4 + w;
  f16* p = k + (size_t)row * N_DIM + lane * 4;
  f16x4 h = *reinterpret_cast<const f16x4*>(p);
  const float x0 = (float)h[0], x1 = (float)h[1], x2 = (float)h[2], x3 = (float)h[3];
  float ss = x0 * x0 + x1 * x1 + x2 * x2 + x3 * x3;
  #pragma unroll
  for (int m = 1; m < 64; m <<= 1) ss += __shfl_xor(ss, m, 64);
  const float inv = 1.0f / (sqrtf(ss) + 1e-6f);
  h[0] = (f16)(x0 * inv); h[1] = (f16)(x1 * inv);
  h[2] = (f16)(x2 * inv); h[3] = (f16)(x3 * inv);
  *reinterpret_cast<f16x4*>(p) = h;
}

// ---------------------------------------------------------------------------
// Kernel 3: per-(batch,chunk) WY factors (unchanged).
// ---------------------------------------------------------------------------
__global__ __launch_bounds__(256, 2) void precompute_wg(
    const f16* __restrict__ kn, const f16* __restrict__ q,
    f16* __restrict__ Wg, f16* __restrict__ Gg) {
  __shared__ __align__(16) f16 Kh[32 * LDK];
  __shared__ __align__(16) f16 Qh[32 * LDK];
  __shared__ float Al[32 * 33];

  const int tid  = threadIdx.x;
  const int lane = tid & 63;
  const int w    = tid >> 6;
  const int lr   = lane & 15;
  const int lq   = lane >> 4;
  const int tm   = w >> 1, tn = w & 1;
  const int b    = blockIdx.x >> 4;
  const int c    = blockIdx.x & 15;
  const int t0g  = c * CHUNK;

  {
    const int t = tid >> 3, cg = tid & 7;
    const f16* ks = kn + (size_t)(t0g + t) * ST + b * N_DIM + cg * 32;
    const f16* qs = q  + (size_t)(t0g + t) * ST + b * N_DIM + cg * 32;
    #pragma unroll
    for (int m = 0; m < 4; ++m) {
      *(f16x8*)&Kh[t * LDK + cg * 32 + 8 * m] = ((const f16x8*)ks)[m];
      *(f16x8*)&Qh[t * LDK + cg * 32 + 8 * m] = ((const f16x8*)qs)[m];
    }
  }
  __syncthreads();

  f32x4 Aa = {0.f, 0.f, 0.f, 0.f}, Ga = {0.f, 0.f, 0.f, 0.f};
  #pragma unroll
  for (int kk = 0; kk < 8; ++kk) {
    f16x8 ka = *(const f16x8*)&Kh[(16 * tm + lr) * LDK + 32 * kk + 8 * lq];
    f16x8 qa = *(const f16x8*)&Qh[(16 * tm + lr) * LDK + 32 * kk + 8 * lq];
    f16x8 kb = *(const f16x8*)&Kh[(16 * tn + lr) * LDK + 32 * kk + 8 * lq];
    Aa = __builtin_amdgcn_mfma_f32_16x16x32_f16(ka, kb, Aa, 0, 0, 0);
    Ga = __builtin_amdgcn_mfma_f32_16x16x32_f16(qa, kb, Ga, 0, 0, 0);
  }
  {
    const int s = 16 * tn + lr;
    f16* gdst = Gg + (size_t)blockIdx.x * 1280;
    #pragma unroll
    for (int r = 0; r < 4; ++r) {
      const int t = 16 * tm + 4 * lq + r;
      Al[t * 33 + s] = (s < t) ? Aa[r] : 0.f;
      gdst[t * LDT + s] = (f16)((s <= t) ? Ga[r] : 0.f);
    }
  }
  __syncthreads();

  if (tid < 32) {
    float wv[32];
    f16* wdst = Wg + (size_t)blockIdx.x * 1280;
    #pragma unroll
    for (int t = 0; t < 32; ++t) {
      float s0 = 0.f, s1 = 0.f, s2 = 0.f, s3 = 0.f;
      #pragma unroll
      for (int s = 0; s < 32; ++s) {
        if (s >= t) break;
        const float a = Al[t * 33 + s];
        if ((s & 3) == 0) s0 = fmaf(a, wv[s], s0);
        else if ((s & 3) == 1) s1 = fmaf(a, wv[s], s1);
        else if ((s & 3) == 2) s2 = fmaf(a, wv[s], s2);
        else s3 = fmaf(a, wv[s], s3);
      }
      wv[t] = ((t == tid) ? 1.f : 0.f) - ((s0 + s1) + (s2 + s3));
    }
    #pragma unroll
    for (int t = 0; t < 32; ++t) wdst[t * LDT + tid] = (f16)wv[t];
  }
}

// ---------------------------------------------------------------------------
// Kernel 4: chunked delta-rule scan (unchanged from round 5).
// ---------------------------------------------------------------------------
__global__ __launch_bounds__(256, 1) void scan_chunked(
    const f16* __restrict__ kn, const f16* __restrict__ v,
    const f16* __restrict__ q, const float* __restrict__ S0,
    const f16* __restrict__ Wg, const f16* __restrict__ Gg,
    float* __restrict__ out) {
  __shared__ __align__(16) f16 Kh[32 * LDK];
  __shared__ __align__(16) f16 Qh[32 * LDK];
  __shared__ __align__(16) f16 Sh[32 * LDK];
  __shared__ __align__(16) f16 KhT[256 * LDT];
  __shared__ __align__(16) f16 Wl[32 * LDT];
  __shared__ __align__(16) f16 Gl[32 * LDT];
  __shared__ __align__(16) f16 U0T[32 * LDT];
  __shared__ __align__(16) f16 UT[32 * LDT];
  __shared__ __align__(16) float Vl[32 * LDV];

  const int tid  = threadIdx.x;
  const int lane = tid & 63;
  const int w    = tid >> 6;
  const int lr   = lane & 15;
  const int lq   = lane >> 4;
  const int tm   = w >> 1, tn = w & 1;
  const int b    = blockIdx.x & 31;
  const int i0   = (blockIdx.x >> 5) * IBLK;

  f32x4 acc[2][4];
  const float* S0b = S0 + (size_t)b * N_DIM * N_DIM + (size_t)i0 * N_DIM;
  #pragma unroll
  for (int ti = 0; ti < 2; ++ti)
    #pragma unroll
    for (int jt = 0; jt < 4; ++jt)
      #pragma unroll
      for (int r = 0; r < 4; ++r) {
        const int i = 16 * ti + 4 * lq + r;
        const int j = 64 * w + 16 * jt + lr;
        acc[ti][jt][r] = S0b[(size_t)i * N_DIM + j];
      }
  {
    const int i = tid >> 3, cg = tid & 7;
    const float* ss = S0b + (size_t)i * N_DIM + cg * 32;
    #pragma unroll
    for (int m = 0; m < 4; ++m) {
      float4 f0 = *(const float4*)(ss + 8 * m);
      float4 f1 = *(const float4*)(ss + 8 * m + 4);
      *(f16x8*)&Sh[i * LDK + cg * 32 + 8 * m] = cvt8(f0, f1);
    }
  }
  __syncthreads();

  for (int c = 0; c < NCHUNK; ++c) {
    const int t0g = c * CHUNK;
    {
      const int t = tid >> 3, cg = tid & 7;
      const f16* ks = kn + (size_t)(t0g + t) * ST + b * N_DIM + cg * 32;
      const f16* qs = q  + (size_t)(t0g + t) * ST + b * N_DIM + cg * 32;
      #pragma unroll
      for (int m = 0; m < 4; ++m) {
        *(f16x8*)&Kh[t * LDK + cg * 32 + 8 * m] = ((const f16x8*)ks)[m];
        *(f16x8*)&Qh[t * LDK + cg * 32 + 8 * m] = ((const f16x8*)qs)[m];
      }
      const f16x4 vf = *(const f16x4*)(v + (size_t)(t0g + t) * ST + b * N_DIM + i0 + cg * 4);
      *(float4*)&Vl[t * LDV + cg * 4] =
          make_float4((float)vf[0], (float)vf[1], (float)vf[2], (float)vf[3]);
    }
    {
      const f16* col = kn + (size_t)t0g * ST + b * N_DIM + tid;
      #pragma unroll
      for (int m = 0; m < 4; ++m) {
        f16x8 h;
        #pragma unroll
        for (int e = 0; e < 8; ++e) h[e] = col[(size_t)(8 * m + e) * ST];
        *(f16x8*)&KhT[tid * LDT + 8 * m] = h;
      }
    }
    if (tid < 160) {
      const f16x8* wsrc = (const f16x8*)(Wg + (size_t)(b * NCHUNK + c) * 1280);
      const f16x8* gsrc = (const f16x8*)(Gg + (size_t)(b * NCHUNK + c) * 1280);
      ((f16x8*)Wl)[tid] = wsrc[tid];
      ((f16x8*)Gl)[tid] = gsrc[tid];
    }
    __syncthreads();

    f32x4 Pacc = {0.f, 0.f, 0.f, 0.f};
    f32x4 Oq   = {0.f, 0.f, 0.f, 0.f};
    #pragma unroll
    for (int kk = 0; kk < 8; ++kk) {
      f16x8 ka = *(const f16x8*)&Kh[(16 * tm + lr) * LDK + 32 * kk + 8 * lq];
      f16x8 qa = *(const f16x8*)&Qh[(16 * tm + lr) * LDK + 32 * kk + 8 * lq];
      f16x8 sb = *(const f16x8*)&Sh[(16 * tn + lr) * LDK + 32 * kk + 8 * lq];
      Pacc = __builtin_amdgcn_mfma_f32_16x16x32_f16(ka, sb, Pacc, 0, 0, 0);
      Oq   = __builtin_amdgcn_mfma_f32_16x16x32_f16(qa, sb, Oq,   0, 0, 0);
    }
    {
      const int i = 16 * tn + lr;
      const int t0 = 16 * tm + 4 * lq;
      f16x4 u0;
      #pragma unroll
      for (int r = 0; r < 4; ++r) u0[r] = (f16)(Vl[(t0 + r) * LDV + i] - Pacc[r]);
      *(f16x4*)&U0T[i * LDT + t0] = u0;
    }
    __syncthreads();

    {
      f16x8 wa = *(const f16x8*)&Wl[(16 * tm + lr) * LDT + 8 * lq];
      f16x8 ub = *(const f16x8*)&U0T[(16 * tn + lr) * LDT + 8 * lq];
      f32x4 z = {0.f, 0.f, 0.f, 0.f};
      f32x4 Ud = __builtin_amdgcn_mfma_f32_16x16x32_f16(wa, ub, z, 0, 0, 0);
      const int i = 16 * tn + lr;
      const int t0 = 16 * tm + 4 * lq;
      f16x4 uh;
      #pragma unroll
      for (int r = 0; r < 4; ++r) uh[r] = (f16)Ud[r];
      *(f16x4*)&UT[i * LDT + t0] = uh;
    }
    __syncthreads();

    {
      f16x8 ga = *(const f16x8*)&Gl[(16 * tm + lr) * LDT + 8 * lq];
      f16x8 ub = *(const f16x8*)&UT[(16 * tn + lr) * LDT + 8 * lq];
      f32x4 O = __builtin_amdgcn_mfma_f32_16x16x32_f16(ga, ub, Oq, 0, 0, 0);
      const int i = 16 * tn + lr;
      const int tt0 = 16 * tm + 4 * lq;
      #pragma unroll
      for (int r = 0; r < 4; ++r) {
        const float sq = O[r];
        const float sig = 1.0f / (1.0f + __expf(-sq));
        out[(size_t)(t0g + tt0 + r) * ST + b * N_DIM + i0 + i] = sq * sq * sig;
      }
    }
    #pragma unroll
    for (int ti = 0; ti < 2; ++ti) {
      f16x8 ua = *(const f16x8*)&UT[(16 * ti + lr) * LDT + 8 * lq];
      #pragma unroll
      for (int jt = 0; jt < 4; ++jt) {
        f16x8 kb = *(const f16x8*)&KhT[(64 * w + 16 * jt + lr) * LDT + 8 * lq];
        acc[ti][jt] = __builtin_amdgcn_mfma_f32_16x16x32_f16(ua, kb, acc[ti][jt], 0, 0, 0);
      }
    }
    #pragma unroll
    for (int ti = 0; ti < 2; ++ti)
      #pragma unroll
      for (int jt = 0; jt < 4; ++jt)
        #pragma unroll
        for (int r = 0; r < 4; ++r)
          Sh[(16 * ti + 4 * lq + r) * LDK + 64 * w + 16 * jt + lr] = (f16)acc[ti][jt][r];
    __syncthreads();
  }
}

// ---------------------------------------------------------------------------
extern "C" void kernel_launch(void* const* d_in, const int* in_sizes, int n_in,
                              void* d_out, int out_size, void* d_ws, size_t ws_size,
                              hipStream_t stream) {
  (void)in_sizes; (void)n_in; (void)out_size; (void)ws_size;
  const float* x  = (const float*)d_in[0];
  const float* S0 = (const float*)d_in[1];
  const float* Wk = (const float*)d_in[2];
  const float* Wv = (const float*)d_in[3];
  const float* Wq = (const float*)d_in[4];
  float* outp = (float*)d_out;

  // ws: kn | v | q (f16, 3 x 8.4MB) | Wg | Gg (f16) | Wh (f16, 1.5MB)
  f16* kn = (f16*)d_ws;
  f16* vv = kn + (size_t)M_DIM * N_DIM;
  f16* qq = vv + (size_t)M_DIM * N_DIM;
  f16* Wg = qq + (size_t)M_DIM * N_DIM;
  f16* Gg = Wg + (size_t)B_DIM * NCHUNK * 1280;
  f16* Wh = Gg + (size_t)B_DIM * NCHUNK * 1280;

  dim3 gw(N_DIM * D_DIM / 8 / 256, 3);
  cvt_w_kernel<<<gw, 256, 0, stream>>>(Wk, Wv, Wq, Wh);
  dim3 gg(M_DIM / 128, 6);
  proj_gemm_mfma<<<gg, 256, 0, stream>>>(x, Wh, kn, vv, qq);
  knorm_kernel<<<M_DIM / 4, 256, 0, stream>>>(kn);
  precompute_wg<<<B_DIM * NCHUNK, 256, 0, stream>>>(kn, qq, Wg, Gg);
  scan_chunked<<<B_DIM * (N_DIM / IBLK), 256, 0, stream>>>(kn, vv, qq, S0, Wg, Gg, outp);
}